// Round 6
// baseline (1911.273 us; speedup 1.0000x reference)
//
#include <hip/hip_runtime.h>
#include <math.h>

#define BB 4
#define NN 2048
#define EE 16384
#define LL (EE + NN)      // 18432
#define ND_ 256
#define ED_ 128
#define TD_ 64
#define CC 512
#define HH 8
#define DH_ 64
#define C4 2048

typedef unsigned short u16;
typedef unsigned int u32;
typedef __bf16 bhalf8 __attribute__((ext_vector_type(8)));
typedef float f32x4 __attribute__((ext_vector_type(4)));

struct GatherArgs {
    const float* x;      // (B,N,ND)
    const float* ts;     // (B,N)
    const float* wtemb;  // (TD)
    const float* btemb;  // (TD)
    const float* eattr;  // (B,E,ED)
    const int*   ei;     // (B,2,E)
};

__device__ __forceinline__ u16 f2bf(float f) {
    union { float f; unsigned u; } c; c.f = f;
    const unsigned r = (c.u + 0x7fffu + ((c.u >> 16) & 1u)) >> 16;   // RNE
    return (u16)r;
}
__device__ __forceinline__ u16 f2bf_hw(float f) {      // native cvt (RNE)
    __bf16 h = (__bf16)f;
    union { __bf16 h; u16 u; } c; c.h = h; return c.u;
}
__device__ __forceinline__ float bf2f(u16 u) {
    union { unsigned u; float f; } c; c.u = ((unsigned)u) << 16; return c.f;
}
// tanh-form GELU: |err vs exact-erf gelu| ~3e-4, far below bf16 rounding
__device__ __forceinline__ float gelu_fast(float v) {
    const float u = v * (0.7978845608f + 0.0356774081f * v * v);
    const float e = __expf(2.0f * u);
    const float t = 1.0f - 2.0f / (e + 1.0f);
    return 0.5f * v * (1.0f + t);
}

#define GLD16(gp, lp) __builtin_amdgcn_global_load_lds( \
    (const __attribute__((address_space(1))) unsigned int*)(gp), \
    (__attribute__((address_space(3))) unsigned int*)(lp), 16, 0, 0)

// ---------------------------------------------------------------------------
// bf16 MFMA GEMM, counted-vmcnt deep pipeline (T3+T4+T5):
//   Y[M x N](bf16) = A[M x K] @ W[N x K]^T + bias(f32)
// 256x256 block, 512 thr = 8 waves (2M x 4N), per-wave 128x64 output.
// BK=64, double-buffered 128 KB LDS. Raw s_barrier + s_waitcnt vmcnt(8):
// each wave keeps one full K-tile (8 global_load_lds) in flight across the
// barrier — never drains to 0 in steady state (m218's +38-73% lever).
// 4 phases per K-tile: ds_read one 64x32 C-quadrant's frags -> 16 MFMA,
// wrapped in s_setprio(1/0). M%256==0, N%256==0, K%64==0, K>=128.
// ---------------------------------------------------------------------------
template<bool GELU>
__global__ __launch_bounds__(512, 2)
void gemm_mfma(const u16* __restrict__ A, const u16* __restrict__ W,
               const float* __restrict__ bias, u16* __restrict__ Y,
               int N, int K)
{
    __shared__ u16 As[2][16384];   // 256 rows x 64 bf16, x2 buffers (64 KB)
    __shared__ u16 Bs[2][16384];   // 64 KB

    // bijective XCD-chunked swizzle (m204)
    const int o    = blockIdx.y * gridDim.x + blockIdx.x;
    const int nwg  = gridDim.x * gridDim.y;
    const int xcd  = o & 7;
    const int qq   = nwg >> 3, rr = nwg & 7;
    const int wg   = (xcd < rr ? xcd * (qq + 1) : rr * (qq + 1) + (xcd - rr) * qq) + (o >> 3);
    const int bx   = wg % gridDim.x;
    const int by   = wg / gridDim.x;
    const int m0   = by * 256;
    const int n0   = bx * 256;

    const int tid  = threadIdx.x;
    const int lane = tid & 63;
    const int wid  = tid >> 6;          // 0..7
    const int wm   = wid >> 2;          // wave row: 2 x 128 rows
    const int wn   = wid & 3;           // wave col: 4 x 64 cols

    const size_t sK = (size_t)K;
    const u16* Agb = A + (size_t)(m0 + (tid >> 3)) * sK + (tid & 7) * 8;
    const u16* Wgb = W + (size_t)(n0 + (tid >> 3)) * sK + (tid & 7) * 8;

    const int NT  = K >> 6;             // K-tiles of 64
    const int rlo = lane & 15;
    const int kb8 = (lane >> 4) * 8;

#define STAGE(ktile, buf) do {                                   \
    const u16* _ag = Agb + (size_t)(ktile) * 64;                 \
    const u16* _wg = Wgb + (size_t)(ktile) * 64;                 \
    u16* _la = &As[buf][tid * 8];                                \
    u16* _lb = &Bs[buf][tid * 8];                                \
    GLD16(_ag,            _la);                                  \
    GLD16(_ag +  64 * sK, _la + 4096);                           \
    GLD16(_ag + 128 * sK, _la + 8192);                           \
    GLD16(_ag + 192 * sK, _la + 12288);                          \
    GLD16(_wg,            _lb);                                  \
    GLD16(_wg +  64 * sK, _lb + 4096);                           \
    GLD16(_wg + 128 * sK, _lb + 8192);                           \
    GLD16(_wg + 192 * sK, _lb + 12288);                          \
} while (0)

    f32x4 acc[8][4] = {};

    // prologue: tiles 0 and 1 in flight; wait for tile 0 only (vmcnt(8))
    STAGE(0, 0);
    STAGE(1, 1);
    asm volatile("s_waitcnt vmcnt(8)" ::: "memory");
    __builtin_amdgcn_s_barrier();
    __builtin_amdgcn_sched_barrier(0);

    int cur = 0;
    for (int kt = 0; kt < NT; ++kt) {
        const u16* as = &As[cur][0];
        const u16* bs = &Bs[cur][0];

        #pragma unroll
        for (int p = 0; p < 4; ++p) {           // 4 C-quadrants (64x32) x K=64
            const int qm = p >> 1, qn = p & 1;
            bhalf8 a[4][2], b[2][2];
            #pragma unroll
            for (int i = 0; i < 4; ++i)
                #pragma unroll
                for (int ks = 0; ks < 2; ++ks)
                    a[i][ks] = *(const bhalf8*)&as[(wm * 128 + qm * 64 + i * 16 + rlo) * 64 + ks * 32 + kb8];
            #pragma unroll
            for (int j = 0; j < 2; ++j)
                #pragma unroll
                for (int ks = 0; ks < 2; ++ks)
                    b[j][ks] = *(const bhalf8*)&bs[(wn * 64 + qn * 32 + j * 16 + rlo) * 64 + ks * 32 + kb8];

            __builtin_amdgcn_s_setprio(1);
            #pragma unroll
            for (int i = 0; i < 4; ++i)
                #pragma unroll
                for (int j = 0; j < 2; ++j)
                    #pragma unroll
                    for (int ks = 0; ks < 2; ++ks)   // swapped operands: row-major D
                        acc[qm * 4 + i][qn * 2 + j] =
                            __builtin_amdgcn_mfma_f32_16x16x32_bf16(b[j][ks], a[i][ks],
                                                                    acc[qm * 4 + i][qn * 2 + j], 0, 0, 0);
            __builtin_amdgcn_s_setprio(0);
        }

        if (kt == NT - 1) break;
        __builtin_amdgcn_sched_barrier(0);
        __builtin_amdgcn_s_barrier();            // all waves done reading buf[cur]
        __builtin_amdgcn_sched_barrier(0);
        if (kt + 2 < NT) {
            STAGE(kt + 2, cur);                  // refill just-freed buffer
            asm volatile("s_waitcnt vmcnt(8)" ::: "memory");   // tile kt+1 landed; kt+2 in flight
        } else {
            asm volatile("s_waitcnt vmcnt(0)" ::: "memory");   // epilogue drain
        }
        __builtin_amdgcn_s_barrier();            // tile kt+1 visible to all waves
        __builtin_amdgcn_sched_barrier(0);
        cur ^= 1;
    }
#undef STAGE

    // Epilogue: row = m0+wm*128+i*16+(lane&15); cols = n0+wn*64+j*16+(lane>>4)*4
    const int row0 = m0 + wm * 128;
    const int col0 = n0 + wn * 64;
    const int rq   = (lane >> 4) * 4;
    float4 bi[4];
    #pragma unroll
    for (int j = 0; j < 4; ++j)
        bi[j] = *(const float4*)(bias + col0 + j * 16 + rq);

    #pragma unroll
    for (int i = 0; i < 8; ++i) {
        const int gr = row0 + i * 16 + rlo;
        u16* yrow = Y + (size_t)gr * N + col0;
        #pragma unroll
        for (int j = 0; j < 4; ++j) {
            float v0 = acc[i][j][0] + bi[j].x;
            float v1 = acc[i][j][1] + bi[j].y;
            float v2 = acc[i][j][2] + bi[j].z;
            float v3 = acc[i][j][3] + bi[j].w;
            if constexpr (GELU) {
                v0 = gelu_fast(v0); v1 = gelu_fast(v1);
                v2 = gelu_fast(v2); v3 = gelu_fast(v3);
            }
            ushort4 ov;
            ov.x = f2bf_hw(v0); ov.y = f2bf_hw(v1);
            ov.z = f2bf_hw(v2); ov.w = f2bf_hw(v3);
            *(ushort4*)(yrow + j * 16 + rq) = ov;
        }
    }
}

// ---------------------------------------------------------------------------
// Prep: row order r = 4*edge_local + batch. Builds bf16 A_node (rows x 512)
// and A_kv = [time|edge] (rows x 256).
// ---------------------------------------------------------------------------
__global__ __launch_bounds__(256)
void prep_kernel(u16* __restrict__ An, u16* __restrict__ Akv,
                 int e0, GatherArgs ga)
{
    const int r  = blockIdx.x;
    const int el = r >> 2;
    const int b  = r & 3;
    const int ge = e0 + el;
    const int t  = threadIdx.x;

    int isrc, itgt;
    if (ge < EE) {
        isrc = ga.ei[(b * 2 + 0) * EE + ge];
        itgt = ga.ei[(b * 2 + 1) * EE + ge];
    } else {
        isrc = itgt = ge - EE;
    }

    if (t < 128) {
        const int c = t * 4;
        const float* src = (c < ND_) ? (ga.x + ((size_t)b * NN + isrc) * ND_ + c)
                                     : (ga.x + ((size_t)b * NN + itgt) * ND_ + (c - ND_));
        const float4 vv = *(const float4*)src;
        ushort4 ov;
        ov.x = f2bf(vv.x); ov.y = f2bf(vv.y); ov.z = f2bf(vv.z); ov.w = f2bf(vv.w);
        *(ushort4*)(An + (size_t)r * 512 + c) = ov;
    } else if (t < 160) {
        const int c  = (t - 128) * 4;
        const float tt = (c < TD_) ? ga.ts[b * NN + isrc] : ga.ts[b * NN + itgt];
        const int  cb = (c < TD_) ? c : c - TD_;
        ushort4 ov;
        ov.x = f2bf(sinf(tt * ga.wtemb[cb + 0] + ga.btemb[cb + 0]));
        ov.y = f2bf(sinf(tt * ga.wtemb[cb + 1] + ga.btemb[cb + 1]));
        ov.z = f2bf(sinf(tt * ga.wtemb[cb + 2] + ga.btemb[cb + 2]));
        ov.w = f2bf(sinf(tt * ga.wtemb[cb + 3] + ga.btemb[cb + 3]));
        *(ushort4*)(Akv + (size_t)r * 256 + c) = ov;
    } else if (t < 192) {
        const int c = (t - 160) * 4;
        float4 vv = make_float4(0.f, 0.f, 0.f, 0.f);
        if (ge < EE) vv = *(const float4*)(ga.eattr + ((size_t)b * EE + ge) * ED_ + c);
        ushort4 ov;
        ov.x = f2bf(vv.x); ov.y = f2bf(vv.y); ov.z = f2bf(vv.z); ov.w = f2bf(vv.w);
        *(ushort4*)(Akv + (size_t)r * 256 + 128 + c) = ov;
    }
}

// ---------------------------------------------------------------------------
// Weight folding / conversion helpers
// ---------------------------------------------------------------------------
__global__ __launch_bounds__(256)
void comb_w_bf(const float* __restrict__ Wa, const float* __restrict__ Wb,
               u16* __restrict__ out, int Kin, int ostride)
{
    const int idx  = blockIdx.x * 256 + threadIdx.x;
    const int c    = idx / Kin;
    const int kcol = idx - c * Kin;
    float acc = 0.f;
    for (int j = 0; j < CC; j++)
        acc += Wa[c * CC + j] * Wb[j * Kin + kcol];
    out[(size_t)c * ostride + kcol] = f2bf(acc);
}

__global__ __launch_bounds__(256)
void comb_b(const float* __restrict__ Wa, const float* __restrict__ bin,
            const float* __restrict__ ba, float* __restrict__ bout)
{
    const int c = blockIdx.x * 256 + threadIdx.x;
    float acc = ba[c];
    for (int j = 0; j < CC; j++)
        acc += Wa[c * CC + j] * bin[j];
    bout[c] = acc;
}

__global__ __launch_bounds__(256)
void cvt_bf(const float* __restrict__ in, u16* __restrict__ out, int n)
{
    const int i = (blockIdx.x * 256 + threadIdx.x) * 4;
    if (i < n) {
        const float4 v = *(const float4*)(in + i);
        ushort4 ov;
        ov.x = f2bf(v.x); ov.y = f2bf(v.y); ov.z = f2bf(v.z); ov.w = f2bf(v.w);
        *(ushort4*)(out + i) = ov;
    }
}

__global__ __launch_bounds__(256)
void zero_u16(u16* __restrict__ p, int n)
{
    const int i = blockIdx.x * 256 + threadIdx.x;
    if (i < n) p[i] = 0;
}

__global__ __launch_bounds__(256)
void copy_f32(const float* __restrict__ in, float* __restrict__ out, int n)
{
    const int i = blockIdx.x * 256 + threadIdx.x;
    if (i < n) out[i] = in[i];
}

// ---------------------------------------------------------------------------
// Batch-axis attention, rows 4e..4e+3 adjacent. Block = 4 edges x 64 lanes.
// ---------------------------------------------------------------------------
__global__ __launch_bounds__(256)
void attn_kernel(const u16* __restrict__ nodq, const u16* __restrict__ kv,
                 u16* __restrict__ ctx)
{
    const int e    = blockIdx.x * 4 + (threadIdx.x >> 6);
    const int lane = threadIdx.x & 63;
    const int off  = (lane >> 3) * 64 + (lane & 7) * 8;   // u16 offset in row

    float qf[4][8], kf[4][8], vf[4][8];
    #pragma unroll
    for (int l = 0; l < 4; l++) {
        const size_t rq = (size_t)(4 * e + l) * 1024;
        const uint4 qv = *(const uint4*)(nodq + rq + 512 + off);
        const uint4 kx = *(const uint4*)(kv + rq + off);
        const uint4 vx = *(const uint4*)(kv + rq + 512 + off);
        const u32 qa[4] = {qv.x, qv.y, qv.z, qv.w};
        const u32 ka[4] = {kx.x, kx.y, kx.z, kx.w};
        const u32 va[4] = {vx.x, vx.y, vx.z, vx.w};
        #pragma unroll
        for (int p = 0; p < 4; p++) {
            qf[l][2*p] = bf2f((u16)qa[p]); qf[l][2*p+1] = bf2f((u16)(qa[p] >> 16));
            kf[l][2*p] = bf2f((u16)ka[p]); kf[l][2*p+1] = bf2f((u16)(ka[p] >> 16));
            vf[l][2*p] = bf2f((u16)va[p]); vf[l][2*p+1] = bf2f((u16)(va[p] >> 16));
        }
    }

    float sc[4][4];
    #pragma unroll
    for (int l = 0; l < 4; l++) {
        #pragma unroll
        for (int m = 0; m < 4; m++) {
            float p = 0.f;
            #pragma unroll
            for (int d = 0; d < 8; d++) p += qf[l][d] * kf[m][d];
            p += __shfl_xor(p, 1, 64);
            p += __shfl_xor(p, 2, 64);
            p += __shfl_xor(p, 4, 64);
            sc[l][m] = p * 0.125f;
        }
    }

    #pragma unroll
    for (int l = 0; l < 4; l++) {
        const float mx = fmaxf(fmaxf(sc[l][0], sc[l][1]), fmaxf(sc[l][2], sc[l][3]));
        float a[4], s = 0.f;
        #pragma unroll
        for (int m = 0; m < 4; m++) { a[m] = __expf(sc[l][m] - mx); s += a[m]; }
        const float inv = 1.0f / s;
        float cv[8];
        #pragma unroll
        for (int d = 0; d < 8; d++) {
            cv[d] = (a[0] * vf[0][d] + a[1] * vf[1][d] +
                     a[2] * vf[2][d] + a[3] * vf[3][d]) * inv;
        }
        ushort4 o0, o1;
        o0.x = f2bf(cv[0]); o0.y = f2bf(cv[1]); o0.z = f2bf(cv[2]); o0.w = f2bf(cv[3]);
        o1.x = f2bf(cv[4]); o1.y = f2bf(cv[5]); o1.z = f2bf(cv[6]); o1.w = f2bf(cv[7]);
        u16* crow = ctx + (size_t)(4 * e + l) * 512 + off;
        *(ushort4*)crow       = o0;
        *(ushort4*)(crow + 4) = o1;
    }
}

// ---------------------------------------------------------------------------
// ln1: out1 = LN(nodef + attn_out) -> bf16 only (256 thr, 2 cols/thread)
// ---------------------------------------------------------------------------
__global__ __launch_bounds__(256)
void ln1_kernel(const u16* __restrict__ nodq, const u16* __restrict__ aout,
                const float* __restrict__ g, const float* __restrict__ be,
                u16* __restrict__ outb)
{
    const int r = blockIdx.x;
    const int t = threadIdx.x;
    const int c = t * 2;

    const u32 nf = *(const u32*)(nodq + (size_t)r * 1024 + c);
    const u32 ao = *(const u32*)(aout + (size_t)r * 512 + c);
    const float v0 = bf2f((u16)nf) + bf2f((u16)ao);
    const float v1 = bf2f((u16)(nf >> 16)) + bf2f((u16)(ao >> 16));

    __shared__ float red[4];
    float s = v0 + v1;
    #pragma unroll
    for (int o = 32; o; o >>= 1) s += __shfl_xor(s, o, 64);
    const int wid = t >> 6, lane = t & 63;
    if (lane == 0) red[wid] = s;
    __syncthreads();
    const float mean = (red[0] + red[1] + red[2] + red[3]) * (1.0f / 512.0f);

    const float d0 = v0 - mean, d1 = v1 - mean;
    float vs = d0 * d0 + d1 * d1;
    #pragma unroll
    for (int o = 32; o; o >>= 1) vs += __shfl_xor(vs, o, 64);
    __syncthreads();
    if (lane == 0) red[wid] = vs;
    __syncthreads();
    const float var = (red[0] + red[1] + red[2] + red[3]) * (1.0f / 512.0f);
    const float rstd = rsqrtf(var + 1e-5f);

    const float y0 = d0 * rstd * g[c]     + be[c];
    const float y1 = d1 * rstd * g[c + 1] + be[c + 1];
    ushort2 ov; ov.x = f2bf(y0); ov.y = f2bf(y1);
    *(ushort2*)(outb + (size_t)r * 512 + c) = ov;
}

// ---------------------------------------------------------------------------
// ln2: d_out[grow] = LN(out1 + ffn) (f32 out; sole writer of d_out)
// ---------------------------------------------------------------------------
__global__ __launch_bounds__(256)
void ln2_kernel(const u16* __restrict__ out1, const u16* __restrict__ ffn,
                const float* __restrict__ g, const float* __restrict__ be,
                float* __restrict__ out, int e0)
{
    const int r = blockIdx.x;
    const int t = threadIdx.x;
    const int c = t * 2;

    const u32 o1 = *(const u32*)(out1 + (size_t)r * 512 + c);
    const u32 ff = *(const u32*)(ffn  + (size_t)r * 512 + c);
    const float v0 = bf2f((u16)o1) + bf2f((u16)ff);
    const float v1 = bf2f((u16)(o1 >> 16)) + bf2f((u16)(ff >> 16));

    __shared__ float red[4];
    float s = v0 + v1;
    #pragma unroll
    for (int o = 32; o; o >>= 1) s += __shfl_xor(s, o, 64);
    const int wid = t >> 6, lane = t & 63;
    if (lane == 0) red[wid] = s;
    __syncthreads();
    const float mean = (red[0] + red[1] + red[2] + red[3]) * (1.0f / 512.0f);

    const float d0 = v0 - mean, d1 = v1 - mean;
    float vs = d0 * d0 + d1 * d1;
    #pragma unroll
    for (int o = 32; o; o >>= 1) vs += __shfl_xor(vs, o, 64);
    __syncthreads();
    if (lane == 0) red[wid] = vs;
    __syncthreads();
    const float var = (red[0] + red[1] + red[2] + red[3]) * (1.0f / 512.0f);
    const float rstd = rsqrtf(var + 1e-5f);

    const int el = r >> 2;
    const int b  = r & 3;
    float2 ov;
    ov.x = d0 * rstd * g[c]     + be[c];
    ov.y = d1 * rstd * g[c + 1] + be[c + 1];
    *(float2*)(out + ((size_t)b * LL + e0 + el) * CC + c) = ov;
}

// ---------------------------------------------------------------------------
extern "C" void kernel_launch(void* const* d_in, const int* in_sizes, int n_in,
                              void* d_out, int out_size, void* d_ws, size_t ws_size,
                              hipStream_t stream)
{
    const float* x       = (const float*)d_in[0];
    const float* eattr   = (const float*)d_in[1];
    const float* ts      = (const float*)d_in[2];
    const float* W_node  = (const float*)d_in[3];
    const float* b_node  = (const float*)d_in[4];
    const float* W_temb  = (const float*)d_in[5];
    const float* b_temb  = (const float*)d_in[6];
    const float* W_timef = (const float*)d_in[7];
    const float* b_timef = (const float*)d_in[8];
    const float* W_edge  = (const float*)d_in[9];
    const float* b_edge  = (const float*)d_in[10];
    const float* Wq      = (const float*)d_in[11];
    const float* bq      = (const float*)d_in[12];
    const float* Wk      = (const float*)d_in[13];
    const float* bk      = (const float*)d_in[14];
    const float* Wv      = (const float*)d_in[15];
    const float* bv      = (const float*)d_in[16];
    const float* Wo      = (const float*)d_in[17];
    const float* bo      = (const float*)d_in[18];
    const float* W1      = (const float*)d_in[19];
    const float* b1      = (const float*)d_in[20];
    const float* W2      = (const float*)d_in[21];
    const float* b2      = (const float*)d_in[22];
    const float* g1      = (const float*)d_in[23];
    const float* be1     = (const float*)d_in[24];
    const float* g2      = (const float*)d_in[25];
    const float* be2     = (const float*)d_in[26];
    const int*   ei      = (const int*)d_in[27];

    float* out = (float*)d_out;

    // ---- weight region (bf16) at front of ws ----
    u16* wnq_cat = (u16*)d_ws;              // 1024x512  [W_node ; Wq@W_node]
    u16* wkv_cat = wnq_cat + 524288;        // 1024x256  block-diag [Wk@W_timef | Wv@W_edge]
    u16* wo      = wkv_cat + 262144;        // 512x512
    u16* w1b     = wo + 262144;             // 2048x512
    u16* w2b     = w1b + 1048576;           // 512x2048
    float* bias_nq = (float*)(w2b + 1048576);   // 1024
    float* bias_kv = bias_nq + 1024;            // 1024
    char*  cbase   = (char*)(bias_kv + 1024);
    const size_t fixedB = (size_t)(cbase - (char*)d_ws);

    // ---- chunk sizing: per edge = 4 rows x 4096 u16 = 32768 B ----
    const size_t availB = (ws_size > fixedB) ? (ws_size - fixedB) : 0;
    int Ec = (int)(availB / 32768);
    Ec = (Ec / 64) * 64;                    // rows multiple of 256
    if (Ec > LL) Ec = LL;
    if (Ec < 64) Ec = 64;

    const size_t rmax = (size_t)4 * Ec;
    u16* An   = (u16*)cbase;                // rows x 512  (A_node -> ctx -> out1)
    u16* nodq = An + rmax * 512;            // rows x 1024 [nodef | q]
    u16* R    = nodq + rmax * 1024;         // rows x 2048 overlay
    u16* Akv  = R;                          // rows x 256
    u16* kv   = R + rmax * 256;             // rows x 1024 [k | v]
    u16* hid  = R;                          // rows x 2048 (Akv,kv dead by then)
    u16* aout = R + rmax * 2048;            // rows x 512  attn_out -> ffn

    GatherArgs ga{x, ts, W_temb, b_temb, eattr, ei};
    const dim3 blk(256);
    const dim3 gblk(512);

    // ---- weight prep ----
    cvt_bf   <<<dim3(256),  blk, 0, stream>>>(W_node, wnq_cat, 262144);
    comb_w_bf<<<dim3(1024), blk, 0, stream>>>(Wq, W_node, wnq_cat + 262144, 512, 512);
    zero_u16 <<<dim3(1024), blk, 0, stream>>>(wkv_cat, 262144);
    comb_w_bf<<<dim3(256),  blk, 0, stream>>>(Wk, W_timef, wkv_cat, 128, 256);
    comb_w_bf<<<dim3(256),  blk, 0, stream>>>(Wv, W_edge, wkv_cat + 512 * 256 + 128, 128, 256);
    cvt_bf   <<<dim3(256),  blk, 0, stream>>>(Wo, wo,  262144);
    cvt_bf   <<<dim3(1024), blk, 0, stream>>>(W1, w1b, 1048576);
    cvt_bf   <<<dim3(1024), blk, 0, stream>>>(W2, w2b, 1048576);
    copy_f32 <<<dim3(2),    blk, 0, stream>>>(b_node, bias_nq, 512);
    comb_b   <<<dim3(2),    blk, 0, stream>>>(Wq, b_node,  bq, bias_nq + 512);
    comb_b   <<<dim3(2),    blk, 0, stream>>>(Wk, b_timef, bk, bias_kv);
    comb_b   <<<dim3(2),    blk, 0, stream>>>(Wv, b_edge,  bv, bias_kv + 512);

    for (int e0 = 0; e0 < LL; e0 += Ec) {
        int ec = LL - e0; if (ec > Ec) ec = Ec;
        const int rows = 4 * ec;
        const int gy = rows / 256;

        prep_kernel<<<dim3(rows), blk, 0, stream>>>(An, Akv, e0, ga);

        // [nodef|q] = An @ wnq_cat^T ; [k|v] = Akv @ wkv_cat^T
        gemm_mfma<false><<<dim3(4, gy), gblk, 0, stream>>>(An,  wnq_cat, bias_nq, nodq, 1024, 512);
        gemm_mfma<false><<<dim3(4, gy), gblk, 0, stream>>>(Akv, wkv_cat, bias_kv, kv,   1024, 256);

        attn_kernel<<<dim3(ec / 4), blk, 0, stream>>>(nodq, kv, An /*ctx*/);

        // attn_out = ctx @ Wo^T + bo ; out1 = LN(nodef + attn_out) -> An (bf16)
        gemm_mfma<false><<<dim3(2, gy), gblk, 0, stream>>>(An, wo, bo, aout, 512, 512);
        ln1_kernel<<<dim3(rows), blk, 0, stream>>>(nodq, aout, g1, be1, An /*out1*/);

        // FFN: hid = gelu(out1 @ W1^T) ; ffn = hid @ W2^T -> aout
        gemm_mfma<true ><<<dim3(8, gy), gblk, 0, stream>>>(An,  w1b, b1, hid, 2048, 512);
        gemm_mfma<false><<<dim3(2, gy), gblk, 0, stream>>>(hid, w2b, b2, aout /*ffn*/, 512, 2048);

        ln2_kernel<<<dim3(rows), blk, 0, stream>>>(An, aout, g2, be2, out, e0);
    }
}

// Round 7
// 1489.476 us; speedup vs baseline: 1.2832x; 1.2832x over previous
//
#include <hip/hip_runtime.h>
#include <math.h>

#define BB 4
#define NN 2048
#define EE 16384
#define LL (EE + NN)      // 18432
#define ND_ 256
#define ED_ 128
#define TD_ 64
#define CC 512
#define HH 8
#define DH_ 64
#define C4 2048

typedef unsigned short u16;
typedef unsigned int u32;
typedef __bf16 bhalf8 __attribute__((ext_vector_type(8)));
typedef float f32x4 __attribute__((ext_vector_type(4)));

struct GatherArgs {
    const float* x;      // (B,N,ND)
    const float* ts;     // (B,N)
    const float* wtemb;  // (TD)
    const float* btemb;  // (TD)
    const float* eattr;  // (B,E,ED)
    const int*   ei;     // (B,2,E)
};

__device__ __forceinline__ u16 f2bf(float f) {
    union { float f; unsigned u; } c; c.f = f;
    const unsigned r = (c.u + 0x7fffu + ((c.u >> 16) & 1u)) >> 16;   // RNE
    return (u16)r;
}
__device__ __forceinline__ u16 f2bf_hw(float f) {      // native cvt (RNE)
    __bf16 h = (__bf16)f;
    union { __bf16 h; u16 u; } c; c.h = h; return c.u;
}
__device__ __forceinline__ float bf2f(u16 u) {
    union { unsigned u; float f; } c; c.u = ((unsigned)u) << 16; return c.f;
}
// tanh-form GELU: |err vs exact-erf gelu| ~3e-4, far below bf16 rounding
__device__ __forceinline__ float gelu_fast(float v) {
    const float u = v * (0.7978845608f + 0.0356774081f * v * v);
    const float e = __expf(2.0f * u);
    const float t = 1.0f - 2.0f / (e + 1.0f);
    return 0.5f * v * (1.0f + t);
}

#define GLD16(gp, lp) __builtin_amdgcn_global_load_lds( \
    (const __attribute__((address_space(1))) unsigned int*)(gp), \
    (__attribute__((address_space(3))) unsigned int*)(lp), 16, 0, 0)

// ---------------------------------------------------------------------------
// bf16 MFMA GEMM, counted-vmcnt pipeline + T2 XOR swizzle:
//   Y[M x N](bf16) = A[M x K] @ W[N x K]^T + bias(f32)
// 256x256 block, 512 thr = 8 waves (2M x 4N), per-wave 128x64 output.
// BK=64, double-buffered 128 KB LDS. s_waitcnt vmcnt(8) across barriers
// (never 0 in steady state).
// LDS swizzle: tile row r (128 B) is stored with its 16B-chunks permuted by
// c -> c ^ (r&7). global_load_lds writes linearly, so the SOURCE address is
// inverse-swizzled (same involution) and the ds_read applies the XOR
// (rule #21; §6 G4 byte^=(row&7)<<4). row&7 == lane&7 for all fragment rows.
// M%256==0, N%256==0, K%64==0, K>=128.
// ---------------------------------------------------------------------------
template<bool GELU>
__global__ __launch_bounds__(512, 2)
void gemm_mfma(const u16* __restrict__ A, const u16* __restrict__ W,
               const float* __restrict__ bias, u16* __restrict__ Y,
               int N, int K)
{
    __shared__ u16 As[2][16384];   // 256 rows x 64 bf16, x2 buffers (64 KB)
    __shared__ u16 Bs[2][16384];   // 64 KB

    // bijective XCD-chunked swizzle (m204)
    const int o    = blockIdx.y * gridDim.x + blockIdx.x;
    const int nwg  = gridDim.x * gridDim.y;
    const int xcd  = o & 7;
    const int qq   = nwg >> 3, rr = nwg & 7;
    const int wg   = (xcd < rr ? xcd * (qq + 1) : rr * (qq + 1) + (xcd - rr) * qq) + (o >> 3);
    const int bx   = wg % gridDim.x;
    const int by   = wg / gridDim.x;
    const int m0   = by * 256;
    const int n0   = bx * 256;

    const int tid  = threadIdx.x;
    const int lane = tid & 63;
    const int wid  = tid >> 6;          // 0..7
    const int wm   = wid >> 2;          // wave row: 2 x 128 rows
    const int wn   = wid & 3;           // wave col: 4 x 64 cols

    // staging: thread t covers LDS row t>>3 (+64 per quarter), chunk t&7.
    // inverse-swizzled global column chunk: (t&7) ^ ((t>>3)&7)
    const int swz8 = (((tid & 7) ^ ((tid >> 3) & 7))) * 8;
    const size_t sK = (size_t)K;
    const u16* Agb = A + (size_t)(m0 + (tid >> 3)) * sK + swz8;
    const u16* Wgb = W + (size_t)(n0 + (tid >> 3)) * sK + swz8;

    const int NT  = K >> 6;             // K-tiles of 64
    const int rlo = lane & 15;
    const int hi4 = lane >> 4;          // 0..3
    const int lk  = lane & 7;           // read-side XOR key (== row&7)

#define STAGE(ktile, buf) do {                                   \
    const u16* _ag = Agb + (size_t)(ktile) * 64;                 \
    const u16* _wg = Wgb + (size_t)(ktile) * 64;                 \
    u16* _la = &As[buf][tid * 8];                                \
    u16* _lb = &Bs[buf][tid * 8];                                \
    GLD16(_ag,            _la);                                  \
    GLD16(_ag +  64 * sK, _la + 4096);                           \
    GLD16(_ag + 128 * sK, _la + 8192);                           \
    GLD16(_ag + 192 * sK, _la + 12288);                          \
    GLD16(_wg,            _lb);                                  \
    GLD16(_wg +  64 * sK, _lb + 4096);                           \
    GLD16(_wg + 128 * sK, _lb + 8192);                           \
    GLD16(_wg + 192 * sK, _lb + 12288);                          \
} while (0)

    f32x4 acc[8][4] = {};

    // prologue: tiles 0 and 1 in flight; wait for tile 0 only (vmcnt(8))
    STAGE(0, 0);
    STAGE(1, 1);
    asm volatile("s_waitcnt vmcnt(8)" ::: "memory");
    __builtin_amdgcn_s_barrier();
    __builtin_amdgcn_sched_barrier(0);

    int cur = 0;
    for (int kt = 0; kt < NT; ++kt) {
        const u16* as = &As[cur][0];
        const u16* bs = &Bs[cur][0];

        #pragma unroll
        for (int p = 0; p < 4; ++p) {           // 4 C-quadrants (64x32) x K=64
            const int qm = p >> 1, qn = p & 1;
            bhalf8 a[4][2], b[2][2];
            #pragma unroll
            for (int i = 0; i < 4; ++i)
                #pragma unroll
                for (int ks = 0; ks < 2; ++ks)
                    a[i][ks] = *(const bhalf8*)&as[(wm * 128 + qm * 64 + i * 16 + rlo) * 64
                                                   + ((((ks << 2) | hi4) ^ lk) << 3)];
            #pragma unroll
            for (int j = 0; j < 2; ++j)
                #pragma unroll
                for (int ks = 0; ks < 2; ++ks)
                    b[j][ks] = *(const bhalf8*)&bs[(wn * 64 + qn * 32 + j * 16 + rlo) * 64
                                                   + ((((ks << 2) | hi4) ^ lk) << 3)];

            __builtin_amdgcn_s_setprio(1);
            #pragma unroll
            for (int i = 0; i < 4; ++i)
                #pragma unroll
                for (int j = 0; j < 2; ++j)
                    #pragma unroll
                    for (int ks = 0; ks < 2; ++ks)   // swapped operands: row-major D
                        acc[qm * 4 + i][qn * 2 + j] =
                            __builtin_amdgcn_mfma_f32_16x16x32_bf16(b[j][ks], a[i][ks],
                                                                    acc[qm * 4 + i][qn * 2 + j], 0, 0, 0);
            __builtin_amdgcn_s_setprio(0);
        }

        if (kt == NT - 1) break;
        __builtin_amdgcn_sched_barrier(0);
        __builtin_amdgcn_s_barrier();            // all waves done reading buf[cur]
        __builtin_amdgcn_sched_barrier(0);
        if (kt + 2 < NT) {
            STAGE(kt + 2, cur);                  // refill just-freed buffer
            asm volatile("s_waitcnt vmcnt(8)" ::: "memory");   // tile kt+1 landed; kt+2 in flight
        } else {
            asm volatile("s_waitcnt vmcnt(0)" ::: "memory");   // epilogue drain
        }
        __builtin_amdgcn_s_barrier();            // tile kt+1 visible to all waves
        __builtin_amdgcn_sched_barrier(0);
        cur ^= 1;
    }
#undef STAGE

    // Epilogue: row = m0+wm*128+i*16+(lane&15); cols = n0+wn*64+j*16+(lane>>4)*4
    const int row0 = m0 + wm * 128;
    const int col0 = n0 + wn * 64;
    const int rq   = (lane >> 4) * 4;
    float4 bi[4];
    #pragma unroll
    for (int j = 0; j < 4; ++j)
        bi[j] = *(const float4*)(bias + col0 + j * 16 + rq);

    #pragma unroll
    for (int i = 0; i < 8; ++i) {
        const int gr = row0 + i * 16 + rlo;
        u16* yrow = Y + (size_t)gr * N + col0;
        #pragma unroll
        for (int j = 0; j < 4; ++j) {
            float v0 = acc[i][j][0] + bi[j].x;
            float v1 = acc[i][j][1] + bi[j].y;
            float v2 = acc[i][j][2] + bi[j].z;
            float v3 = acc[i][j][3] + bi[j].w;
            if constexpr (GELU) {
                v0 = gelu_fast(v0); v1 = gelu_fast(v1);
                v2 = gelu_fast(v2); v3 = gelu_fast(v3);
            }
            ushort4 ov;
            ov.x = f2bf_hw(v0); ov.y = f2bf_hw(v1);
            ov.z = f2bf_hw(v2); ov.w = f2bf_hw(v3);
            *(ushort4*)(yrow + j * 16 + rq) = ov;
        }
    }
}

// ---------------------------------------------------------------------------
// Prep: row order r = 4*edge_local + batch. Builds bf16 A_node (rows x 512)
// and A_kv = [time|edge] (rows x 256).
// ---------------------------------------------------------------------------
__global__ __launch_bounds__(256)
void prep_kernel(u16* __restrict__ An, u16* __restrict__ Akv,
                 int e0, GatherArgs ga)
{
    const int r  = blockIdx.x;
    const int el = r >> 2;
    const int b  = r & 3;
    const int ge = e0 + el;
    const int t  = threadIdx.x;

    int isrc, itgt;
    if (ge < EE) {
        isrc = ga.ei[(b * 2 + 0) * EE + ge];
        itgt = ga.ei[(b * 2 + 1) * EE + ge];
    } else {
        isrc = itgt = ge - EE;
    }

    if (t < 128) {
        const int c = t * 4;
        const float* src = (c < ND_) ? (ga.x + ((size_t)b * NN + isrc) * ND_ + c)
                                     : (ga.x + ((size_t)b * NN + itgt) * ND_ + (c - ND_));
        const float4 vv = *(const float4*)src;
        ushort4 ov;
        ov.x = f2bf(vv.x); ov.y = f2bf(vv.y); ov.z = f2bf(vv.z); ov.w = f2bf(vv.w);
        *(ushort4*)(An + (size_t)r * 512 + c) = ov;
    } else if (t < 160) {
        const int c  = (t - 128) * 4;
        const float tt = (c < TD_) ? ga.ts[b * NN + isrc] : ga.ts[b * NN + itgt];
        const int  cb = (c < TD_) ? c : c - TD_;
        ushort4 ov;
        ov.x = f2bf(sinf(tt * ga.wtemb[cb + 0] + ga.btemb[cb + 0]));
        ov.y = f2bf(sinf(tt * ga.wtemb[cb + 1] + ga.btemb[cb + 1]));
        ov.z = f2bf(sinf(tt * ga.wtemb[cb + 2] + ga.btemb[cb + 2]));
        ov.w = f2bf(sinf(tt * ga.wtemb[cb + 3] + ga.btemb[cb + 3]));
        *(ushort4*)(Akv + (size_t)r * 256 + c) = ov;
    } else if (t < 192) {
        const int c = (t - 160) * 4;
        float4 vv = make_float4(0.f, 0.f, 0.f, 0.f);
        if (ge < EE) vv = *(const float4*)(ga.eattr + ((size_t)b * EE + ge) * ED_ + c);
        ushort4 ov;
        ov.x = f2bf(vv.x); ov.y = f2bf(vv.y); ov.z = f2bf(vv.z); ov.w = f2bf(vv.w);
        *(ushort4*)(Akv + (size_t)r * 256 + 128 + c) = ov;
    }
}

// ---------------------------------------------------------------------------
// Weight folding / conversion helpers
// ---------------------------------------------------------------------------
__global__ __launch_bounds__(256)
void comb_w_bf(const float* __restrict__ Wa, const float* __restrict__ Wb,
               u16* __restrict__ out, int Kin, int ostride)
{
    const int idx  = blockIdx.x * 256 + threadIdx.x;
    const int c    = idx / Kin;
    const int kcol = idx - c * Kin;
    float acc = 0.f;
    for (int j = 0; j < CC; j++)
        acc += Wa[c * CC + j] * Wb[j * Kin + kcol];
    out[(size_t)c * ostride + kcol] = f2bf(acc);
}

__global__ __launch_bounds__(256)
void comb_b(const float* __restrict__ Wa, const float* __restrict__ bin,
            const float* __restrict__ ba, float* __restrict__ bout)
{
    const int c = blockIdx.x * 256 + threadIdx.x;
    float acc = ba[c];
    for (int j = 0; j < CC; j++)
        acc += Wa[c * CC + j] * bin[j];
    bout[c] = acc;
}

__global__ __launch_bounds__(256)
void cvt_bf(const float* __restrict__ in, u16* __restrict__ out, int n)
{
    const int i = (blockIdx.x * 256 + threadIdx.x) * 4;
    if (i < n) {
        const float4 v = *(const float4*)(in + i);
        ushort4 ov;
        ov.x = f2bf(v.x); ov.y = f2bf(v.y); ov.z = f2bf(v.z); ov.w = f2bf(v.w);
        *(ushort4*)(out + i) = ov;
    }
}

__global__ __launch_bounds__(256)
void zero_u16(u16* __restrict__ p, int n)
{
    const int i = blockIdx.x * 256 + threadIdx.x;
    if (i < n) p[i] = 0;
}

__global__ __launch_bounds__(256)
void copy_f32(const float* __restrict__ in, float* __restrict__ out, int n)
{
    const int i = blockIdx.x * 256 + threadIdx.x;
    if (i < n) out[i] = in[i];
}

// ---------------------------------------------------------------------------
// Batch-axis attention, rows 4e..4e+3 adjacent. Block = 4 edges x 64 lanes.
// ---------------------------------------------------------------------------
__global__ __launch_bounds__(256)
void attn_kernel(const u16* __restrict__ nodq, const u16* __restrict__ kv,
                 u16* __restrict__ ctx)
{
    const int e    = blockIdx.x * 4 + (threadIdx.x >> 6);
    const int lane = threadIdx.x & 63;
    const int off  = (lane >> 3) * 64 + (lane & 7) * 8;   // u16 offset in row

    float qf[4][8], kf[4][8], vf[4][8];
    #pragma unroll
    for (int l = 0; l < 4; l++) {
        const size_t rq = (size_t)(4 * e + l) * 1024;
        const uint4 qv = *(const uint4*)(nodq + rq + 512 + off);
        const uint4 kx = *(const uint4*)(kv + rq + off);
        const uint4 vx = *(const uint4*)(kv + rq + 512 + off);
        const u32 qa[4] = {qv.x, qv.y, qv.z, qv.w};
        const u32 ka[4] = {kx.x, kx.y, kx.z, kx.w};
        const u32 va[4] = {vx.x, vx.y, vx.z, vx.w};
        #pragma unroll
        for (int p = 0; p < 4; p++) {
            qf[l][2*p] = bf2f((u16)qa[p]); qf[l][2*p+1] = bf2f((u16)(qa[p] >> 16));
            kf[l][2*p] = bf2f((u16)ka[p]); kf[l][2*p+1] = bf2f((u16)(ka[p] >> 16));
            vf[l][2*p] = bf2f((u16)va[p]); vf[l][2*p+1] = bf2f((u16)(va[p] >> 16));
        }
    }

    float sc[4][4];
    #pragma unroll
    for (int l = 0; l < 4; l++) {
        #pragma unroll
        for (int m = 0; m < 4; m++) {
            float p = 0.f;
            #pragma unroll
            for (int d = 0; d < 8; d++) p += qf[l][d] * kf[m][d];
            p += __shfl_xor(p, 1, 64);
            p += __shfl_xor(p, 2, 64);
            p += __shfl_xor(p, 4, 64);
            sc[l][m] = p * 0.125f;
        }
    }

    #pragma unroll
    for (int l = 0; l < 4; l++) {
        const float mx = fmaxf(fmaxf(sc[l][0], sc[l][1]), fmaxf(sc[l][2], sc[l][3]));
        float a[4], s = 0.f;
        #pragma unroll
        for (int m = 0; m < 4; m++) { a[m] = __expf(sc[l][m] - mx); s += a[m]; }
        const float inv = 1.0f / s;
        float cv[8];
        #pragma unroll
        for (int d = 0; d < 8; d++) {
            cv[d] = (a[0] * vf[0][d] + a[1] * vf[1][d] +
                     a[2] * vf[2][d] + a[3] * vf[3][d]) * inv;
        }
        ushort4 o0, o1;
        o0.x = f2bf(cv[0]); o0.y = f2bf(cv[1]); o0.z = f2bf(cv[2]); o0.w = f2bf(cv[3]);
        o1.x = f2bf(cv[4]); o1.y = f2bf(cv[5]); o1.z = f2bf(cv[6]); o1.w = f2bf(cv[7]);
        u16* crow = ctx + (size_t)(4 * e + l) * 512 + off;
        *(ushort4*)crow       = o0;
        *(ushort4*)(crow + 4) = o1;
    }
}

// ---------------------------------------------------------------------------
// ln1: out1 = LN(nodef + attn_out) -> bf16 only (256 thr, 2 cols/thread)
// ---------------------------------------------------------------------------
__global__ __launch_bounds__(256)
void ln1_kernel(const u16* __restrict__ nodq, const u16* __restrict__ aout,
                const float* __restrict__ g, const float* __restrict__ be,
                u16* __restrict__ outb)
{
    const int r = blockIdx.x;
    const int t = threadIdx.x;
    const int c = t * 2;

    const u32 nf = *(const u32*)(nodq + (size_t)r * 1024 + c);
    const u32 ao = *(const u32*)(aout + (size_t)r * 512 + c);
    const float v0 = bf2f((u16)nf) + bf2f((u16)ao);
    const float v1 = bf2f((u16)(nf >> 16)) + bf2f((u16)(ao >> 16));

    __shared__ float red[4];
    float s = v0 + v1;
    #pragma unroll
    for (int o = 32; o; o >>= 1) s += __shfl_xor(s, o, 64);
    const int wid = t >> 6, lane = t & 63;
    if (lane == 0) red[wid] = s;
    __syncthreads();
    const float mean = (red[0] + red[1] + red[2] + red[3]) * (1.0f / 512.0f);

    const float d0 = v0 - mean, d1 = v1 - mean;
    float vs = d0 * d0 + d1 * d1;
    #pragma unroll
    for (int o = 32; o; o >>= 1) vs += __shfl_xor(vs, o, 64);
    __syncthreads();
    if (lane == 0) red[wid] = vs;
    __syncthreads();
    const float var = (red[0] + red[1] + red[2] + red[3]) * (1.0f / 512.0f);
    const float rstd = rsqrtf(var + 1e-5f);

    const float y0 = d0 * rstd * g[c]     + be[c];
    const float y1 = d1 * rstd * g[c + 1] + be[c + 1];
    ushort2 ov; ov.x = f2bf(y0); ov.y = f2bf(y1);
    *(ushort2*)(outb + (size_t)r * 512 + c) = ov;
}

// ---------------------------------------------------------------------------
// ln2: d_out[grow] = LN(out1 + ffn) (f32 out; sole writer of d_out)
// ---------------------------------------------------------------------------
__global__ __launch_bounds__(256)
void ln2_kernel(const u16* __restrict__ out1, const u16* __restrict__ ffn,
                const float* __restrict__ g, const float* __restrict__ be,
                float* __restrict__ out, int e0)
{
    const int r = blockIdx.x;
    const int t = threadIdx.x;
    const int c = t * 2;

    const u32 o1 = *(const u32*)(out1 + (size_t)r * 512 + c);
    const u32 ff = *(const u32*)(ffn  + (size_t)r * 512 + c);
    const float v0 = bf2f((u16)o1) + bf2f((u16)ff);
    const float v1 = bf2f((u16)(o1 >> 16)) + bf2f((u16)(ff >> 16));

    __shared__ float red[4];
    float s = v0 + v1;
    #pragma unroll
    for (int o = 32; o; o >>= 1) s += __shfl_xor(s, o, 64);
    const int wid = t >> 6, lane = t & 63;
    if (lane == 0) red[wid] = s;
    __syncthreads();
    const float mean = (red[0] + red[1] + red[2] + red[3]) * (1.0f / 512.0f);

    const float d0 = v0 - mean, d1 = v1 - mean;
    float vs = d0 * d0 + d1 * d1;
    #pragma unroll
    for (int o = 32; o; o >>= 1) vs += __shfl_xor(vs, o, 64);
    __syncthreads();
    if (lane == 0) red[wid] = vs;
    __syncthreads();
    const float var = (red[0] + red[1] + red[2] + red[3]) * (1.0f / 512.0f);
    const float rstd = rsqrtf(var + 1e-5f);

    const int el = r >> 2;
    const int b  = r & 3;
    float2 ov;
    ov.x = d0 * rstd * g[c]     + be[c];
    ov.y = d1 * rstd * g[c + 1] + be[c + 1];
    *(float2*)(out + ((size_t)b * LL + e0 + el) * CC + c) = ov;
}

// ---------------------------------------------------------------------------
extern "C" void kernel_launch(void* const* d_in, const int* in_sizes, int n_in,
                              void* d_out, int out_size, void* d_ws, size_t ws_size,
                              hipStream_t stream)
{
    const float* x       = (const float*)d_in[0];
    const float* eattr   = (const float*)d_in[1];
    const float* ts      = (const float*)d_in[2];
    const float* W_node  = (const float*)d_in[3];
    const float* b_node  = (const float*)d_in[4];
    const float* W_temb  = (const float*)d_in[5];
    const float* b_temb  = (const float*)d_in[6];
    const float* W_timef = (const float*)d_in[7];
    const float* b_timef = (const float*)d_in[8];
    const float* W_edge  = (const float*)d_in[9];
    const float* b_edge  = (const float*)d_in[10];
    const float* Wq      = (const float*)d_in[11];
    const float* bq      = (const float*)d_in[12];
    const float* Wk      = (const float*)d_in[13];
    const float* bk      = (const float*)d_in[14];
    const float* Wv      = (const float*)d_in[15];
    const float* bv      = (const float*)d_in[16];
    const float* Wo      = (const float*)d_in[17];
    const float* bo      = (const float*)d_in[18];
    const float* W1      = (const float*)d_in[19];
    const float* b1      = (const float*)d_in[20];
    const float* W2      = (const float*)d_in[21];
    const float* b2      = (const float*)d_in[22];
    const float* g1      = (const float*)d_in[23];
    const float* be1     = (const float*)d_in[24];
    const float* g2      = (const float*)d_in[25];
    const float* be2     = (const float*)d_in[26];
    const int*   ei      = (const int*)d_in[27];

    float* out = (float*)d_out;

    // ---- weight region (bf16) at front of ws ----
    u16* wnq_cat = (u16*)d_ws;              // 1024x512  [W_node ; Wq@W_node]
    u16* wkv_cat = wnq_cat + 524288;        // 1024x256  block-diag [Wk@W_timef | Wv@W_edge]
    u16* wo      = wkv_cat + 262144;        // 512x512
    u16* w1b     = wo + 262144;             // 2048x512
    u16* w2b     = w1b + 1048576;           // 512x2048
    float* bias_nq = (float*)(w2b + 1048576);   // 1024
    float* bias_kv = bias_nq + 1024;            // 1024
    char*  cbase   = (char*)(bias_kv + 1024);
    const size_t fixedB = (size_t)(cbase - (char*)d_ws);

    // ---- chunk sizing: per edge = 4 rows x 4096 u16 = 32768 B ----
    const size_t availB = (ws_size > fixedB) ? (ws_size - fixedB) : 0;
    int Ec = (int)(availB / 32768);
    Ec = (Ec / 64) * 64;                    // rows multiple of 256
    if (Ec > LL) Ec = LL;
    if (Ec < 64) Ec = 64;

    const size_t rmax = (size_t)4 * Ec;
    u16* An   = (u16*)cbase;                // rows x 512  (A_node -> ctx -> out1)
    u16* nodq = An + rmax * 512;            // rows x 1024 [nodef | q]
    u16* R    = nodq + rmax * 1024;         // rows x 2048 overlay
    u16* Akv  = R;                          // rows x 256
    u16* kv   = R + rmax * 256;             // rows x 1024 [k | v]
    u16* hid  = R;                          // rows x 2048 (Akv,kv dead by then)
    u16* aout = R + rmax * 2048;            // rows x 512  attn_out -> ffn

    GatherArgs ga{x, ts, W_temb, b_temb, eattr, ei};
    const dim3 blk(256);
    const dim3 gblk(512);

    // ---- weight prep ----
    cvt_bf   <<<dim3(256),  blk, 0, stream>>>(W_node, wnq_cat, 262144);
    comb_w_bf<<<dim3(1024), blk, 0, stream>>>(Wq, W_node, wnq_cat + 262144, 512, 512);
    zero_u16 <<<dim3(1024), blk, 0, stream>>>(wkv_cat, 262144);
    comb_w_bf<<<dim3(256),  blk, 0, stream>>>(Wk, W_timef, wkv_cat, 128, 256);
    comb_w_bf<<<dim3(256),  blk, 0, stream>>>(Wv, W_edge, wkv_cat + 512 * 256 + 128, 128, 256);
    cvt_bf   <<<dim3(256),  blk, 0, stream>>>(Wo, wo,  262144);
    cvt_bf   <<<dim3(1024), blk, 0, stream>>>(W1, w1b, 1048576);
    cvt_bf   <<<dim3(1024), blk, 0, stream>>>(W2, w2b, 1048576);
    copy_f32 <<<dim3(2),    blk, 0, stream>>>(b_node, bias_nq, 512);
    comb_b   <<<dim3(2),    blk, 0, stream>>>(Wq, b_node,  bq, bias_nq + 512);
    comb_b   <<<dim3(2),    blk, 0, stream>>>(Wk, b_timef, bk, bias_kv);
    comb_b   <<<dim3(2),    blk, 0, stream>>>(Wv, b_edge,  bv, bias_kv + 512);

    for (int e0 = 0; e0 < LL; e0 += Ec) {
        int ec = LL - e0; if (ec > Ec) ec = Ec;
        const int rows = 4 * ec;
        const int gy = rows / 256;

        prep_kernel<<<dim3(rows), blk, 0, stream>>>(An, Akv, e0, ga);

        // [nodef|q] = An @ wnq_cat^T ; [k|v] = Akv @ wkv_cat^T
        gemm_mfma<false><<<dim3(4, gy), gblk, 0, stream>>>(An,  wnq_cat, bias_nq, nodq, 1024, 512);
        gemm_mfma<false><<<dim3(4, gy), gblk, 0, stream>>>(Akv, wkv_cat, bias_kv, kv,   1024, 256);

        attn_kernel<<<dim3(ec / 4), blk, 0, stream>>>(nodq, kv, An /*ctx*/);

        // attn_out = ctx @ Wo^T + bo ; out1 = LN(nodef + attn_out) -> An (bf16)
        gemm_mfma<false><<<dim3(2, gy), gblk, 0, stream>>>(An, wo, bo, aout, 512, 512);
        ln1_kernel<<<dim3(rows), blk, 0, stream>>>(nodq, aout, g1, be1, An /*out1*/);

        // FFN: hid = gelu(out1 @ W1^T) ; ffn = hid @ W2^T -> aout
        gemm_mfma<true ><<<dim3(8, gy), gblk, 0, stream>>>(An,  w1b, b1, hid, 2048, 512);
        gemm_mfma<false><<<dim3(2, gy), gblk, 0, stream>>>(hid, w2b, b2, aout /*ffn*/, 512, 2048);

        ln2_kernel<<<dim3(rows), blk, 0, stream>>>(An, aout, g2, be2, out, e0);
    }
}

// Round 8
// 1443.973 us; speedup vs baseline: 1.3236x; 1.0315x over previous
//
#include <hip/hip_runtime.h>
#include <math.h>

#define BB 4
#define NN 2048
#define EE 16384
#define LL (EE + NN)      // 18432
#define ND_ 256
#define ED_ 128
#define TD_ 64
#define CC 512
#define HH 8
#define DH_ 64
#define C4 2048

typedef unsigned short u16;
typedef unsigned int u32;
typedef __bf16 bhalf8 __attribute__((ext_vector_type(8)));
typedef float f32x4 __attribute__((ext_vector_type(4)));

struct GatherArgs {
    const float* x;      // (B,N,ND)
    const float* ts;     // (B,N)
    const float* wtemb;  // (TD)
    const float* btemb;  // (TD)
    const float* eattr;  // (B,E,ED)
    const int*   ei;     // (B,2,E)
};

__device__ __forceinline__ u16 f2bf(float f) {
    union { float f; unsigned u; } c; c.f = f;
    const unsigned r = (c.u + 0x7fffu + ((c.u >> 16) & 1u)) >> 16;   // RNE
    return (u16)r;
}
__device__ __forceinline__ u16 f2bf_hw(float f) {      // native cvt (RNE)
    __bf16 h = (__bf16)f;
    union { __bf16 h; u16 u; } c; c.h = h; return c.u;
}
__device__ __forceinline__ float bf2f(u16 u) {
    union { unsigned u; float f; } c; c.u = ((unsigned)u) << 16; return c.f;
}
// tanh-form GELU: |err vs exact-erf gelu| ~3e-4, far below bf16 rounding
__device__ __forceinline__ float gelu_fast(float v) {
    const float u = v * (0.7978845608f + 0.0356774081f * v * v);
    const float e = __expf(2.0f * u);
    const float t = 1.0f - 2.0f / (e + 1.0f);
    return 0.5f * v * (1.0f + t);
}

#define GLD16(gp, lp) __builtin_amdgcn_global_load_lds( \
    (const __attribute__((address_space(1))) unsigned int*)(gp), \
    (__attribute__((address_space(3))) unsigned int*)(lp), 16, 0, 0)

// ---------------------------------------------------------------------------
// bf16 MFMA GEMM, counted-vmcnt pipeline + T2 XOR swizzle + hoisted frags:
//   Y[M x N](bf16) = A[M x K] @ W[N x K]^T + bias(f32)
// 256x256 block, 512 thr = 8 waves (2M x 4N), per-wave 128x64 output.
// BK=64, double-buffered 128 KB LDS (1 block/CU). s_waitcnt vmcnt(8)
// across barriers (never 0 in steady state).
// Frag loads hoisted: 24 ds_read_b128/wave/K-tile (a[8][2]+b[4][2]) — the
// minimum for this decomposition — then one 64-MFMA setprio cluster.
// LDS swizzle: 16B-chunk c of row r stored at c^(r&7); global source is
// inverse-swizzled, ds_read applies the XOR (rule #21). row&7 == lane&7.
// M%256==0, N%256==0, K%64==0, K>=128.
// ---------------------------------------------------------------------------
template<bool GELU>
__global__ __launch_bounds__(512, 1)
void gemm_mfma(const u16* __restrict__ A, const u16* __restrict__ W,
               const float* __restrict__ bias, u16* __restrict__ Y,
               int N, int K)
{
    __shared__ u16 As[2][16384];   // 256 rows x 64 bf16, x2 buffers (64 KB)
    __shared__ u16 Bs[2][16384];   // 64 KB

    // bijective XCD-chunked swizzle (m204)
    const int o    = blockIdx.y * gridDim.x + blockIdx.x;
    const int nwg  = gridDim.x * gridDim.y;
    const int xcd  = o & 7;
    const int qq   = nwg >> 3, rr = nwg & 7;
    const int wg   = (xcd < rr ? xcd * (qq + 1) : rr * (qq + 1) + (xcd - rr) * qq) + (o >> 3);
    const int bx   = wg % gridDim.x;
    const int by   = wg / gridDim.x;
    const int m0   = by * 256;
    const int n0   = bx * 256;

    const int tid  = threadIdx.x;
    const int lane = tid & 63;
    const int wid  = tid >> 6;          // 0..7
    const int wm   = wid >> 2;          // wave row: 2 x 128 rows
    const int wn   = wid & 3;           // wave col: 4 x 64 cols

    // staging: thread t covers LDS row t>>3 (+64 per quarter), chunk t&7.
    // inverse-swizzled global column chunk: (t&7) ^ ((t>>3)&7)
    const int swz8 = (((tid & 7) ^ ((tid >> 3) & 7))) * 8;
    const size_t sK = (size_t)K;
    const u16* Agb = A + (size_t)(m0 + (tid >> 3)) * sK + swz8;
    const u16* Wgb = W + (size_t)(n0 + (tid >> 3)) * sK + swz8;

    const int NT  = K >> 6;             // K-tiles of 64
    const int rlo = lane & 15;
    const int hi4 = lane >> 4;          // 0..3
    const int lk  = lane & 7;           // read-side XOR key (== row&7)

#define STAGE(ktile, buf) do {                                   \
    const u16* _ag = Agb + (size_t)(ktile) * 64;                 \
    const u16* _wg = Wgb + (size_t)(ktile) * 64;                 \
    u16* _la = &As[buf][tid * 8];                                \
    u16* _lb = &Bs[buf][tid * 8];                                \
    GLD16(_ag,            _la);                                  \
    GLD16(_ag +  64 * sK, _la + 4096);                           \
    GLD16(_ag + 128 * sK, _la + 8192);                           \
    GLD16(_ag + 192 * sK, _la + 12288);                          \
    GLD16(_wg,            _lb);                                  \
    GLD16(_wg +  64 * sK, _lb + 4096);                           \
    GLD16(_wg + 128 * sK, _lb + 8192);                           \
    GLD16(_wg + 192 * sK, _lb + 12288);                          \
} while (0)

    f32x4 acc[8][4] = {};

    // prologue: tiles 0 and 1 in flight; wait for tile 0 only (vmcnt(8))
    STAGE(0, 0);
    STAGE(1, 1);
    asm volatile("s_waitcnt vmcnt(8)" ::: "memory");
    __builtin_amdgcn_s_barrier();
    __builtin_amdgcn_sched_barrier(0);

    int cur = 0;
    for (int kt = 0; kt < NT; ++kt) {
        const u16* as = &As[cur][0];
        const u16* bs = &Bs[cur][0];

        // Hoisted fragment loads: each distinct frag read exactly once.
        bhalf8 a[8][2], b[4][2];
        #pragma unroll
        for (int i = 0; i < 8; ++i)
            #pragma unroll
            for (int ks = 0; ks < 2; ++ks)
                a[i][ks] = *(const bhalf8*)&as[(wm * 128 + i * 16 + rlo) * 64
                                               + ((((ks << 2) | hi4) ^ lk) << 3)];
        #pragma unroll
        for (int j = 0; j < 4; ++j)
            #pragma unroll
            for (int ks = 0; ks < 2; ++ks)
                b[j][ks] = *(const bhalf8*)&bs[(wn * 64 + j * 16 + rlo) * 64
                                               + ((((ks << 2) | hi4) ^ lk) << 3)];

        __builtin_amdgcn_s_setprio(1);
        #pragma unroll
        for (int i = 0; i < 8; ++i)
            #pragma unroll
            for (int j = 0; j < 4; ++j)
                #pragma unroll
                for (int ks = 0; ks < 2; ++ks)   // swapped operands: row-major D
                    acc[i][j] = __builtin_amdgcn_mfma_f32_16x16x32_bf16(b[j][ks], a[i][ks],
                                                                        acc[i][j], 0, 0, 0);
        __builtin_amdgcn_s_setprio(0);

        if (kt == NT - 1) break;
        __builtin_amdgcn_sched_barrier(0);
        __builtin_amdgcn_s_barrier();            // all waves done reading buf[cur]
        __builtin_amdgcn_sched_barrier(0);
        if (kt + 2 < NT) {
            STAGE(kt + 2, cur);                  // refill just-freed buffer
            asm volatile("s_waitcnt vmcnt(8)" ::: "memory");   // tile kt+1 landed; kt+2 in flight
        } else {
            asm volatile("s_waitcnt vmcnt(0)" ::: "memory");   // epilogue drain
        }
        __builtin_amdgcn_s_barrier();            // tile kt+1 visible to all waves
        __builtin_amdgcn_sched_barrier(0);
        cur ^= 1;
    }
#undef STAGE

    // Epilogue: row = m0+wm*128+i*16+(lane&15); cols = n0+wn*64+j*16+(lane>>4)*4
    const int row0 = m0 + wm * 128;
    const int col0 = n0 + wn * 64;
    const int rq   = (lane >> 4) * 4;
    float4 bi[4];
    #pragma unroll
    for (int j = 0; j < 4; ++j)
        bi[j] = *(const float4*)(bias + col0 + j * 16 + rq);

    #pragma unroll
    for (int i = 0; i < 8; ++i) {
        const int gr = row0 + i * 16 + rlo;
        u16* yrow = Y + (size_t)gr * N + col0;
        #pragma unroll
        for (int j = 0; j < 4; ++j) {
            float v0 = acc[i][j][0] + bi[j].x;
            float v1 = acc[i][j][1] + bi[j].y;
            float v2 = acc[i][j][2] + bi[j].z;
            float v3 = acc[i][j][3] + bi[j].w;
            if constexpr (GELU) {
                v0 = gelu_fast(v0); v1 = gelu_fast(v1);
                v2 = gelu_fast(v2); v3 = gelu_fast(v3);
            }
            ushort4 ov;
            ov.x = f2bf_hw(v0); ov.y = f2bf_hw(v1);
            ov.z = f2bf_hw(v2); ov.w = f2bf_hw(v3);
            *(ushort4*)(yrow + j * 16 + rq) = ov;
        }
    }
}

// ---------------------------------------------------------------------------
// Prep: row order r = 4*edge_local + batch. Builds bf16 A_node (rows x 512)
// and A_kv = [time|edge] (rows x 256).
// ---------------------------------------------------------------------------
__global__ __launch_bounds__(256)
void prep_kernel(u16* __restrict__ An, u16* __restrict__ Akv,
                 int e0, GatherArgs ga)
{
    const int r  = blockIdx.x;
    const int el = r >> 2;
    const int b  = r & 3;
    const int ge = e0 + el;
    const int t  = threadIdx.x;

    int isrc, itgt;
    if (ge < EE) {
        isrc = ga.ei[(b * 2 + 0) * EE + ge];
        itgt = ga.ei[(b * 2 + 1) * EE + ge];
    } else {
        isrc = itgt = ge - EE;
    }

    if (t < 128) {
        const int c = t * 4;
        const float* src = (c < ND_) ? (ga.x + ((size_t)b * NN + isrc) * ND_ + c)
                                     : (ga.x + ((size_t)b * NN + itgt) * ND_ + (c - ND_));
        const float4 vv = *(const float4*)src;
        ushort4 ov;
        ov.x = f2bf(vv.x); ov.y = f2bf(vv.y); ov.z = f2bf(vv.z); ov.w = f2bf(vv.w);
        *(ushort4*)(An + (size_t)r * 512 + c) = ov;
    } else if (t < 160) {
        const int c  = (t - 128) * 4;
        const float tt = (c < TD_) ? ga.ts[b * NN + isrc] : ga.ts[b * NN + itgt];
        const int  cb = (c < TD_) ? c : c - TD_;
        ushort4 ov;
        ov.x = f2bf(sinf(tt * ga.wtemb[cb + 0] + ga.btemb[cb + 0]));
        ov.y = f2bf(sinf(tt * ga.wtemb[cb + 1] + ga.btemb[cb + 1]));
        ov.z = f2bf(sinf(tt * ga.wtemb[cb + 2] + ga.btemb[cb + 2]));
        ov.w = f2bf(sinf(tt * ga.wtemb[cb + 3] + ga.btemb[cb + 3]));
        *(ushort4*)(Akv + (size_t)r * 256 + c) = ov;
    } else if (t < 192) {
        const int c = (t - 160) * 4;
        float4 vv = make_float4(0.f, 0.f, 0.f, 0.f);
        if (ge < EE) vv = *(const float4*)(ga.eattr + ((size_t)b * EE + ge) * ED_ + c);
        ushort4 ov;
        ov.x = f2bf(vv.x); ov.y = f2bf(vv.y); ov.z = f2bf(vv.z); ov.w = f2bf(vv.w);
        *(ushort4*)(Akv + (size_t)r * 256 + 128 + c) = ov;
    }
}

// ---------------------------------------------------------------------------
// Weight folding / conversion helpers
// ---------------------------------------------------------------------------
__global__ __launch_bounds__(256)
void comb_w_bf(const float* __restrict__ Wa, const float* __restrict__ Wb,
               u16* __restrict__ out, int Kin, int ostride)
{
    const int idx  = blockIdx.x * 256 + threadIdx.x;
    const int c    = idx / Kin;
    const int kcol = idx - c * Kin;
    float acc = 0.f;
    for (int j = 0; j < CC; j++)
        acc += Wa[c * CC + j] * Wb[j * Kin + kcol];
    out[(size_t)c * ostride + kcol] = f2bf(acc);
}

__global__ __launch_bounds__(256)
void comb_b(const float* __restrict__ Wa, const float* __restrict__ bin,
            const float* __restrict__ ba, float* __restrict__ bout)
{
    const int c = blockIdx.x * 256 + threadIdx.x;
    float acc = ba[c];
    for (int j = 0; j < CC; j++)
        acc += Wa[c * CC + j] * bin[j];
    bout[c] = acc;
}

__global__ __launch_bounds__(256)
void cvt_bf(const float* __restrict__ in, u16* __restrict__ out, int n)
{
    const int i = (blockIdx.x * 256 + threadIdx.x) * 4;
    if (i < n) {
        const float4 v = *(const float4*)(in + i);
        ushort4 ov;
        ov.x = f2bf(v.x); ov.y = f2bf(v.y); ov.z = f2bf(v.z); ov.w = f2bf(v.w);
        *(ushort4*)(out + i) = ov;
    }
}

__global__ __launch_bounds__(256)
void zero_u16(u16* __restrict__ p, int n)
{
    const int i = blockIdx.x * 256 + threadIdx.x;
    if (i < n) p[i] = 0;
}

__global__ __launch_bounds__(256)
void copy_f32(const float* __restrict__ in, float* __restrict__ out, int n)
{
    const int i = blockIdx.x * 256 + threadIdx.x;
    if (i < n) out[i] = in[i];
}

// ---------------------------------------------------------------------------
// Batch-axis attention, rows 4e..4e+3 adjacent. Block = 4 edges x 64 lanes.
// ---------------------------------------------------------------------------
__global__ __launch_bounds__(256)
void attn_kernel(const u16* __restrict__ nodq, const u16* __restrict__ kv,
                 u16* __restrict__ ctx)
{
    const int e    = blockIdx.x * 4 + (threadIdx.x >> 6);
    const int lane = threadIdx.x & 63;
    const int off  = (lane >> 3) * 64 + (lane & 7) * 8;   // u16 offset in row

    float qf[4][8], kf[4][8], vf[4][8];
    #pragma unroll
    for (int l = 0; l < 4; l++) {
        const size_t rq = (size_t)(4 * e + l) * 1024;
        const uint4 qv = *(const uint4*)(nodq + rq + 512 + off);
        const uint4 kx = *(const uint4*)(kv + rq + off);
        const uint4 vx = *(const uint4*)(kv + rq + 512 + off);
        const u32 qa[4] = {qv.x, qv.y, qv.z, qv.w};
        const u32 ka[4] = {kx.x, kx.y, kx.z, kx.w};
        const u32 va[4] = {vx.x, vx.y, vx.z, vx.w};
        #pragma unroll
        for (int p = 0; p < 4; p++) {
            qf[l][2*p] = bf2f((u16)qa[p]); qf[l][2*p+1] = bf2f((u16)(qa[p] >> 16));
            kf[l][2*p] = bf2f((u16)ka[p]); kf[l][2*p+1] = bf2f((u16)(ka[p] >> 16));
            vf[l][2*p] = bf2f((u16)va[p]); vf[l][2*p+1] = bf2f((u16)(va[p] >> 16));
        }
    }

    float sc[4][4];
    #pragma unroll
    for (int l = 0; l < 4; l++) {
        #pragma unroll
        for (int m = 0; m < 4; m++) {
            float p = 0.f;
            #pragma unroll
            for (int d = 0; d < 8; d++) p += qf[l][d] * kf[m][d];
            p += __shfl_xor(p, 1, 64);
            p += __shfl_xor(p, 2, 64);
            p += __shfl_xor(p, 4, 64);
            sc[l][m] = p * 0.125f;
        }
    }

    #pragma unroll
    for (int l = 0; l < 4; l++) {
        const float mx = fmaxf(fmaxf(sc[l][0], sc[l][1]), fmaxf(sc[l][2], sc[l][3]));
        float a[4], s = 0.f;
        #pragma unroll
        for (int m = 0; m < 4; m++) { a[m] = __expf(sc[l][m] - mx); s += a[m]; }
        const float inv = 1.0f / s;
        float cv[8];
        #pragma unroll
        for (int d = 0; d < 8; d++) {
            cv[d] = (a[0] * vf[0][d] + a[1] * vf[1][d] +
                     a[2] * vf[2][d] + a[3] * vf[3][d]) * inv;
        }
        ushort4 o0, o1;
        o0.x = f2bf(cv[0]); o0.y = f2bf(cv[1]); o0.z = f2bf(cv[2]); o0.w = f2bf(cv[3]);
        o1.x = f2bf(cv[4]); o1.y = f2bf(cv[5]); o1.z = f2bf(cv[6]); o1.w = f2bf(cv[7]);
        u16* crow = ctx + (size_t)(4 * e + l) * 512 + off;
        *(ushort4*)crow       = o0;
        *(ushort4*)(crow + 4) = o1;
    }
}

// ---------------------------------------------------------------------------
// ln1: out1 = LN(nodef + attn_out) -> bf16 only (256 thr, 2 cols/thread)
// ---------------------------------------------------------------------------
__global__ __launch_bounds__(256)
void ln1_kernel(const u16* __restrict__ nodq, const u16* __restrict__ aout,
                const float* __restrict__ g, const float* __restrict__ be,
                u16* __restrict__ outb)
{
    const int r = blockIdx.x;
    const int t = threadIdx.x;
    const int c = t * 2;

    const u32 nf = *(const u32*)(nodq + (size_t)r * 1024 + c);
    const u32 ao = *(const u32*)(aout + (size_t)r * 512 + c);
    const float v0 = bf2f((u16)nf) + bf2f((u16)ao);
    const float v1 = bf2f((u16)(nf >> 16)) + bf2f((u16)(ao >> 16));

    __shared__ float red[4];
    float s = v0 + v1;
    #pragma unroll
    for (int o = 32; o; o >>= 1) s += __shfl_xor(s, o, 64);
    const int wid = t >> 6, lane = t & 63;
    if (lane == 0) red[wid] = s;
    __syncthreads();
    const float mean = (red[0] + red[1] + red[2] + red[3]) * (1.0f / 512.0f);

    const float d0 = v0 - mean, d1 = v1 - mean;
    float vs = d0 * d0 + d1 * d1;
    #pragma unroll
    for (int o = 32; o; o >>= 1) vs += __shfl_xor(vs, o, 64);
    __syncthreads();
    if (lane == 0) red[wid] = vs;
    __syncthreads();
    const float var = (red[0] + red[1] + red[2] + red[3]) * (1.0f / 512.0f);
    const float rstd = rsqrtf(var + 1e-5f);

    const float y0 = d0 * rstd * g[c]     + be[c];
    const float y1 = d1 * rstd * g[c + 1] + be[c + 1];
    ushort2 ov; ov.x = f2bf(y0); ov.y = f2bf(y1);
    *(ushort2*)(outb + (size_t)r * 512 + c) = ov;
}

// ---------------------------------------------------------------------------
// ln2: d_out[grow] = LN(out1 + ffn) (f32 out; sole writer of d_out)
// ---------------------------------------------------------------------------
__global__ __launch_bounds__(256)
void ln2_kernel(const u16* __restrict__ out1, const u16* __restrict__ ffn,
                const float* __restrict__ g, const float* __restrict__ be,
                float* __restrict__ out, int e0)
{
    const int r = blockIdx.x;
    const int t = threadIdx.x;
    const int c = t * 2;

    const u32 o1 = *(const u32*)(out1 + (size_t)r * 512 + c);
    const u32 ff = *(const u32*)(ffn  + (size_t)r * 512 + c);
    const float v0 = bf2f((u16)o1) + bf2f((u16)ff);
    const float v1 = bf2f((u16)(o1 >> 16)) + bf2f((u16)(ff >> 16));

    __shared__ float red[4];
    float s = v0 + v1;
    #pragma unroll
    for (int o = 32; o; o >>= 1) s += __shfl_xor(s, o, 64);
    const int wid = t >> 6, lane = t & 63;
    if (lane == 0) red[wid] = s;
    __syncthreads();
    const float mean = (red[0] + red[1] + red[2] + red[3]) * (1.0f / 512.0f);

    const float d0 = v0 - mean, d1 = v1 - mean;
    float vs = d0 * d0 + d1 * d1;
    #pragma unroll
    for (int o = 32; o; o >>= 1) vs += __shfl_xor(vs, o, 64);
    __syncthreads();
    if (lane == 0) red[wid] = vs;
    __syncthreads();
    const float var = (red[0] + red[1] + red[2] + red[3]) * (1.0f / 512.0f);
    const float rstd = rsqrtf(var + 1e-5f);

    const int el = r >> 2;
    const int b  = r & 3;
    float2 ov;
    ov.x = d0 * rstd * g[c]     + be[c];
    ov.y = d1 * rstd * g[c + 1] + be[c + 1];
    *(float2*)(out + ((size_t)b * LL + e0 + el) * CC + c) = ov;
}

// ---------------------------------------------------------------------------
extern "C" void kernel_launch(void* const* d_in, const int* in_sizes, int n_in,
                              void* d_out, int out_size, void* d_ws, size_t ws_size,
                              hipStream_t stream)
{
    const float* x       = (const float*)d_in[0];
    const float* eattr   = (const float*)d_in[1];
    const float* ts      = (const float*)d_in[2];
    const float* W_node  = (const float*)d_in[3];
    const float* b_node  = (const float*)d_in[4];
    const float* W_temb  = (const float*)d_in[5];
    const float* b_temb  = (const float*)d_in[6];
    const float* W_timef = (const float*)d_in[7];
    const float* b_timef = (const float*)d_in[8];
    const float* W_edge  = (const float*)d_in[9];
    const float* b_edge  = (const float*)d_in[10];
    const float* Wq      = (const float*)d_in[11];
    const float* bq      = (const float*)d_in[12];
    const float* Wk      = (const float*)d_in[13];
    const float* bk      = (const float*)d_in[14];
    const float* Wv      = (const float*)d_in[15];
    const float* bv      = (const float*)d_in[16];
    const float* Wo      = (const float*)d_in[17];
    const float* bo      = (const float*)d_in[18];
    const float* W1      = (const float*)d_in[19];
    const float* b1      = (const float*)d_in[20];
    const float* W2      = (const float*)d_in[21];
    const float* b2      = (const float*)d_in[22];
    const float* g1      = (const float*)d_in[23];
    const float* be1     = (const float*)d_in[24];
    const float* g2      = (const float*)d_in[25];
    const float* be2     = (const float*)d_in[26];
    const int*   ei      = (const int*)d_in[27];

    float* out = (float*)d_out;

    // ---- weight region (bf16) at front of ws ----
    u16* wnq_cat = (u16*)d_ws;              // 1024x512  [W_node ; Wq@W_node]
    u16* wkv_cat = wnq_cat + 524288;        // 1024x256  block-diag [Wk@W_timef | Wv@W_edge]
    u16* wo      = wkv_cat + 262144;        // 512x512
    u16* w1b     = wo + 262144;             // 2048x512
    u16* w2b     = w1b + 1048576;           // 512x2048
    float* bias_nq = (float*)(w2b + 1048576);   // 1024
    float* bias_kv = bias_nq + 1024;            // 1024
    char*  cbase   = (char*)(bias_kv + 1024);
    const size_t fixedB = (size_t)(cbase - (char*)d_ws);

    // ---- chunk sizing: per edge = 4 rows x 4096 u16 = 32768 B ----
    const size_t availB = (ws_size > fixedB) ? (ws_size - fixedB) : 0;
    int Ec = (int)(availB / 32768);
    Ec = (Ec / 64) * 64;                    // rows multiple of 256
    if (Ec > LL) Ec = LL;
    if (Ec < 64) Ec = 64;

    const size_t rmax = (size_t)4 * Ec;
    u16* An   = (u16*)cbase;                // rows x 512  (A_node -> ctx -> out1)
    u16* nodq = An + rmax * 512;            // rows x 1024 [nodef | q]
    u16* R    = nodq + rmax * 1024;         // rows x 2048 overlay
    u16* Akv  = R;                          // rows x 256
    u16* kv   = R + rmax * 256;             // rows x 1024 [k | v]
    u16* hid  = R;                          // rows x 2048 (Akv,kv dead by then)
    u16* aout = R + rmax * 2048;            // rows x 512  attn_out -> ffn

    GatherArgs ga{x, ts, W_temb, b_temb, eattr, ei};
    const dim3 blk(256);
    const dim3 gblk(512);

    // ---- weight prep ----
    cvt_bf   <<<dim3(256),  blk, 0, stream>>>(W_node, wnq_cat, 262144);
    comb_w_bf<<<dim3(1024), blk, 0, stream>>>(Wq, W_node, wnq_cat + 262144, 512, 512);
    zero_u16 <<<dim3(1024), blk, 0, stream>>>(wkv_cat, 262144);
    comb_w_bf<<<dim3(256),  blk, 0, stream>>>(Wk, W_timef, wkv_cat, 128, 256);
    comb_w_bf<<<dim3(256),  blk, 0, stream>>>(Wv, W_edge, wkv_cat + 512 * 256 + 128, 128, 256);
    cvt_bf   <<<dim3(256),  blk, 0, stream>>>(Wo, wo,  262144);
    cvt_bf   <<<dim3(1024), blk, 0, stream>>>(W1, w1b, 1048576);
    cvt_bf   <<<dim3(1024), blk, 0, stream>>>(W2, w2b, 1048576);
    copy_f32 <<<dim3(2),    blk, 0, stream>>>(b_node, bias_nq, 512);
    comb_b   <<<dim3(2),    blk, 0, stream>>>(Wq, b_node,  bq, bias_nq + 512);
    comb_b   <<<dim3(2),    blk, 0, stream>>>(Wk, b_timef, bk, bias_kv);
    comb_b   <<<dim3(2),    blk, 0, stream>>>(Wv, b_edge,  bv, bias_kv + 512);

    for (int e0 = 0; e0 < LL; e0 += Ec) {
        int ec = LL - e0; if (ec > Ec) ec = Ec;
        const int rows = 4 * ec;
        const int gy = rows / 256;

        prep_kernel<<<dim3(rows), blk, 0, stream>>>(An, Akv, e0, ga);

        // [nodef|q] = An @ wnq_cat^T ; [k|v] = Akv @ wkv_cat^T
        gemm_mfma<false><<<dim3(4, gy), gblk, 0, stream>>>(An,  wnq_cat, bias_nq, nodq, 1024, 512);
        gemm_mfma<false><<<dim3(4, gy), gblk, 0, stream>>>(Akv, wkv_cat, bias_kv, kv,   1024, 256);

        attn_kernel<<<dim3(ec / 4), blk, 0, stream>>>(nodq, kv, An /*ctx*/);

        // attn_out = ctx @ Wo^T + bo ; out1 = LN(nodef + attn_out) -> An (bf16)
        gemm_mfma<false><<<dim3(2, gy), gblk, 0, stream>>>(An, wo, bo, aout, 512, 512);
        ln1_kernel<<<dim3(rows), blk, 0, stream>>>(nodq, aout, g1, be1, An /*out1*/);

        // FFN: hid = gelu(out1 @ W1^T) ; ffn = hid @ W2^T -> aout
        gemm_mfma<true ><<<dim3(8, gy), gblk, 0, stream>>>(An,  w1b, b1, hid, 2048, 512);
        gemm_mfma<false><<<dim3(2, gy), gblk, 0, stream>>>(hid, w2b, b2, aout /*ffn*/, 512, 2048);

        ln2_kernel<<<dim3(rows), blk, 0, stream>>>(An, aout, g2, be2, out, e0);
    }
}

// Round 9
// 1402.718 us; speedup vs baseline: 1.3625x; 1.0294x over previous
//
#include <hip/hip_runtime.h>
#include <math.h>

#define BB 4
#define NN 2048
#define EE 16384
#define LL (EE + NN)      // 18432
#define ND_ 256
#define ED_ 128
#define TD_ 64
#define CC 512
#define HH 8
#define DH_ 64
#define C4 2048

typedef unsigned short u16;
typedef unsigned int u32;
typedef __bf16 bhalf8 __attribute__((ext_vector_type(8)));
typedef float f32x4 __attribute__((ext_vector_type(4)));

struct GatherArgs {
    const float* x;      // (B,N,ND)
    const float* ts;     // (B,N)
    const float* wtemb;  // (TD)
    const float* btemb;  // (TD)
    const float* eattr;  // (B,E,ED)
    const int*   ei;     // (B,2,E)
};

__device__ __forceinline__ u16 f2bf(float f) {
    union { float f; unsigned u; } c; c.f = f;
    const unsigned r = (c.u + 0x7fffu + ((c.u >> 16) & 1u)) >> 16;   // RNE
    return (u16)r;
}
__device__ __forceinline__ u16 f2bf_hw(float f) {      // native cvt (RNE)
    __bf16 h = (__bf16)f;
    union { __bf16 h; u16 u; } c; c.h = h; return c.u;
}
__device__ __forceinline__ float bf2f(u16 u) {
    union { unsigned u; float f; } c; c.u = ((unsigned)u) << 16; return c.f;
}
// tanh-form GELU: |err vs exact-erf gelu| ~3e-4, far below bf16 rounding
__device__ __forceinline__ float gelu_fast(float v) {
    const float u = v * (0.7978845608f + 0.0356774081f * v * v);
    const float e = __expf(2.0f * u);
    const float t = 1.0f - 2.0f / (e + 1.0f);
    return 0.5f * v * (1.0f + t);
}

#define GLD16(gp, lp) __builtin_amdgcn_global_load_lds( \
    (const __attribute__((address_space(1))) unsigned int*)(gp), \
    (__attribute__((address_space(3))) unsigned int*)(lp), 16, 0, 0)

// ---------------------------------------------------------------------------
// bf16 MFMA GEMM — 8-phase-per-2-tiles schedule (T2+T3+T4+T5, m201 template):
//   Y[M x N](bf16) = A[M x K] @ W[N x K]^T + bias(f32)
// 256x256 block, 512 thr = 8 waves (2M x 4N), per-wave 128x64 output.
// BK=64, double-buffered 128 KB LDS. Per K-tile 4 phases, each:
//   {ds_read subtile || stage ONE half-tile (2xGLD16)} -> barrier ->
//   lgkmcnt(0) -> setprio(1) -> 16 MFMA -> setprio(0) -> barrier
// Staging staggered by liveness: A[t+1] halves at ph1/ph2 (opposite buffer),
// B[t+2] halves at ph3/ph4 (same buffer, B[t] dead after ph2). One
// s_waitcnt vmcnt(4) per tile at ph4 (B[t+2] pair may stay in flight) —
// never drains to 0 in steady state (T4).
// LDS swizzle (T2): chunk c of row r stored at c^(r&7); inverse-swizzled
// global source, XOR on ds_read (rule #21). 0 bank conflicts (round-7 PMC).
// M%256==0, N%256==0, K%64==0, K>=128.
// ---------------------------------------------------------------------------
template<bool GELU>
__global__ __launch_bounds__(512, 2)
void gemm_mfma(const u16* __restrict__ A, const u16* __restrict__ W,
               const float* __restrict__ bias, u16* __restrict__ Y,
               int N, int K)
{
    __shared__ u16 As[2][16384];   // 256 rows x 64 bf16 per buffer (64 KB)
    __shared__ u16 Bs[2][16384];   // 64 KB

    // bijective XCD-chunked swizzle (m204)
    const int o    = blockIdx.y * gridDim.x + blockIdx.x;
    const int nwg  = gridDim.x * gridDim.y;
    const int xcd  = o & 7;
    const int qq   = nwg >> 3, rr = nwg & 7;
    const int wg   = (xcd < rr ? xcd * (qq + 1) : rr * (qq + 1) + (xcd - rr) * qq) + (o >> 3);
    const int bx   = wg % gridDim.x;
    const int by   = wg / gridDim.x;
    const int m0   = by * 256;
    const int n0   = bx * 256;

    const int tid  = threadIdx.x;
    const int lane = tid & 63;
    const int wid  = tid >> 6;          // 0..7
    const int wm   = wid >> 2;          // wave row: 2 x 128 rows
    const int wn   = wid & 3;           // wave col: 4 x 64 cols

    // staging: thread t covers LDS row t>>3 (+64 per half-step), chunk t&7.
    // inverse-swizzled global column chunk: (t&7) ^ ((t>>3)&7)
    const int swz8 = (((tid & 7) ^ ((tid >> 3) & 7))) * 8;
    const size_t sK = (size_t)K;
    const u16* Agb = A + (size_t)(m0 + (tid >> 3)) * sK + swz8;
    const u16* Wgb = W + (size_t)(n0 + (tid >> 3)) * sK + swz8;

    const int NT  = K >> 6;             // K-tiles of 64
    const int rlo = lane & 15;
    const int hi4 = lane >> 4;          // 0..3
    const int lk  = lane & 7;           // read-side XOR key (== row&7)

// half h of tile kt: rows h*128 .. h*128+127 -> LDS [h*8192 .. h*8192+8191]
#define STAGE_A(kt, h) do {                                      \
    const u16* _g = Agb + (size_t)(kt) * 64 + (size_t)(h) * 128 * sK; \
    u16* _l = &As[(kt) & 1][(h) * 8192 + tid * 8];               \
    GLD16(_g,           _l);                                     \
    GLD16(_g + 64 * sK, _l + 4096);                              \
} while (0)
#define STAGE_B(kt, h) do {                                      \
    const u16* _g = Wgb + (size_t)(kt) * 64 + (size_t)(h) * 128 * sK; \
    u16* _l = &Bs[(kt) & 1][(h) * 8192 + tid * 8];               \
    GLD16(_g,           _l);                                     \
    GLD16(_g + 64 * sK, _l + 4096);                              \
} while (0)

#define SWZOFF(ks) (((((ks) << 2) | hi4) ^ lk) << 3)
#define RD(buf, row, ks) (*(const bhalf8*)&(buf)[(row) * 64 + SWZOFF(ks)])

#define PHASE_SYNC() do {                                        \
    __builtin_amdgcn_sched_barrier(0);                           \
    __builtin_amdgcn_s_barrier();                                \
    asm volatile("s_waitcnt lgkmcnt(0)" ::: "memory");           \
    __builtin_amdgcn_sched_barrier(0);                           \
} while (0)
#define PHASE_END() do {                                         \
    __builtin_amdgcn_sched_barrier(0);                           \
    __builtin_amdgcn_s_barrier();                                \
    __builtin_amdgcn_sched_barrier(0);                           \
} while (0)

    f32x4 acc[8][4] = {};

    // prologue: tile0 fully + B halves of tile1 (A[1] staged in t=0 ph1/ph2)
    STAGE_A(0, 0); STAGE_A(0, 1);
    STAGE_B(0, 0); STAGE_B(0, 1);
    STAGE_B(1, 0); STAGE_B(1, 1);
    asm volatile("s_waitcnt vmcnt(4)" ::: "memory");   // tile0's 8 loads done
    __builtin_amdgcn_s_barrier();
    __builtin_amdgcn_sched_barrier(0);

    for (int t = 0; t < NT; ++t) {
        const u16* as = &As[t & 1][0];
        const u16* bs = &Bs[t & 1][0];
        bhalf8 aLo[4][2], aHi[4][2], b0[2][2], b1[2][2];

        // ---- phase 1: read aLo + b0 ; stage A0[t+1] ; MFMA q(0,0) ----
        #pragma unroll
        for (int i = 0; i < 4; ++i) {
            aLo[i][0] = RD(as, wm * 128 + i * 16 + rlo, 0);
            aLo[i][1] = RD(as, wm * 128 + i * 16 + rlo, 1);
        }
        #pragma unroll
        for (int j = 0; j < 2; ++j) {
            b0[j][0] = RD(bs, wn * 64 + j * 16 + rlo, 0);
            b0[j][1] = RD(bs, wn * 64 + j * 16 + rlo, 1);
        }
        if (t + 1 < NT) STAGE_A(t + 1, 0);
        PHASE_SYNC();
        __builtin_amdgcn_s_setprio(1);
        #pragma unroll
        for (int i = 0; i < 4; ++i)
            #pragma unroll
            for (int j = 0; j < 2; ++j)
                #pragma unroll
                for (int ks = 0; ks < 2; ++ks)
                    acc[i][j] = __builtin_amdgcn_mfma_f32_16x16x32_bf16(b0[j][ks], aLo[i][ks], acc[i][j], 0, 0, 0);
        __builtin_amdgcn_s_setprio(0);
        PHASE_END();

        // ---- phase 2: read b1 ; stage A1[t+1] ; MFMA q(0,1) ----
        #pragma unroll
        for (int j = 0; j < 2; ++j) {
            b1[j][0] = RD(bs, wn * 64 + 32 + j * 16 + rlo, 0);
            b1[j][1] = RD(bs, wn * 64 + 32 + j * 16 + rlo, 1);
        }
        if (t + 1 < NT) STAGE_A(t + 1, 1);
        PHASE_SYNC();
        __builtin_amdgcn_s_setprio(1);
        #pragma unroll
        for (int i = 0; i < 4; ++i)
            #pragma unroll
            for (int j = 0; j < 2; ++j)
                #pragma unroll
                for (int ks = 0; ks < 2; ++ks)
                    acc[i][2 + j] = __builtin_amdgcn_mfma_f32_16x16x32_bf16(b1[j][ks], aLo[i][ks], acc[i][2 + j], 0, 0, 0);
        __builtin_amdgcn_s_setprio(0);
        PHASE_END();

        // ---- phase 3: read aHi ; stage B0[t+2] ; MFMA q(1,0) ----
        #pragma unroll
        for (int i = 0; i < 4; ++i) {
            aHi[i][0] = RD(as, wm * 128 + 64 + i * 16 + rlo, 0);
            aHi[i][1] = RD(as, wm * 128 + 64 + i * 16 + rlo, 1);
        }
        if (t + 2 < NT) STAGE_B(t + 2, 0);
        PHASE_SYNC();
        __builtin_amdgcn_s_setprio(1);
        #pragma unroll
        for (int i = 0; i < 4; ++i)
            #pragma unroll
            for (int j = 0; j < 2; ++j)
                #pragma unroll
                for (int ks = 0; ks < 2; ++ks)
                    acc[4 + i][j] = __builtin_amdgcn_mfma_f32_16x16x32_bf16(b0[j][ks], aHi[i][ks], acc[4 + i][j], 0, 0, 0);
        __builtin_amdgcn_s_setprio(0);
        PHASE_END();

        // ---- phase 4: stage B1[t+2] ; counted vmcnt ; MFMA q(1,1) ----
        if (t + 2 < NT) {
            STAGE_B(t + 2, 1);
            asm volatile("s_waitcnt vmcnt(4)" ::: "memory");  // A[t+1]+older done
        } else if (t < NT - 1) {
            asm volatile("s_waitcnt vmcnt(0)" ::: "memory");  // tail drain
        }
        PHASE_SYNC();
        __builtin_amdgcn_s_setprio(1);
        #pragma unroll
        for (int i = 0; i < 4; ++i)
            #pragma unroll
            for (int j = 0; j < 2; ++j)
                #pragma unroll
                for (int ks = 0; ks < 2; ++ks)
                    acc[4 + i][2 + j] = __builtin_amdgcn_mfma_f32_16x16x32_bf16(b1[j][ks], aHi[i][ks], acc[4 + i][2 + j], 0, 0, 0);
        __builtin_amdgcn_s_setprio(0);
        if (t < NT - 1) PHASE_END();
    }
#undef STAGE_A
#undef STAGE_B
#undef SWZOFF
#undef RD
#undef PHASE_SYNC
#undef PHASE_END

    // Epilogue: row = m0+wm*128+i*16+(lane&15); cols = n0+wn*64+j*16+(lane>>4)*4
    const int row0 = m0 + wm * 128;
    const int col0 = n0 + wn * 64;
    const int rq   = (lane >> 4) * 4;
    float4 bi[4];
    #pragma unroll
    for (int j = 0; j < 4; ++j)
        bi[j] = *(const float4*)(bias + col0 + j * 16 + rq);

    #pragma unroll
    for (int i = 0; i < 8; ++i) {
        const int gr = row0 + i * 16 + rlo;
        u16* yrow = Y + (size_t)gr * N + col0;
        #pragma unroll
        for (int j = 0; j < 4; ++j) {
            float v0 = acc[i][j][0] + bi[j].x;
            float v1 = acc[i][j][1] + bi[j].y;
            float v2 = acc[i][j][2] + bi[j].z;
            float v3 = acc[i][j][3] + bi[j].w;
            if constexpr (GELU) {
                v0 = gelu_fast(v0); v1 = gelu_fast(v1);
                v2 = gelu_fast(v2); v3 = gelu_fast(v3);
            }
            ushort4 ov;
            ov.x = f2bf_hw(v0); ov.y = f2bf_hw(v1);
            ov.z = f2bf_hw(v2); ov.w = f2bf_hw(v3);
            *(ushort4*)(yrow + j * 16 + rq) = ov;
        }
    }
}

// ---------------------------------------------------------------------------
// Prep: row order r = 4*edge_local + batch. Builds bf16 A_node (rows x 512)
// and A_kv = [time|edge] (rows x 256).
// ---------------------------------------------------------------------------
__global__ __launch_bounds__(256)
void prep_kernel(u16* __restrict__ An, u16* __restrict__ Akv,
                 int e0, GatherArgs ga)
{
    const int r  = blockIdx.x;
    const int el = r >> 2;
    const int b  = r & 3;
    const int ge = e0 + el;
    const int t  = threadIdx.x;

    int isrc, itgt;
    if (ge < EE) {
        isrc = ga.ei[(b * 2 + 0) * EE + ge];
        itgt = ga.ei[(b * 2 + 1) * EE + ge];
    } else {
        isrc = itgt = ge - EE;
    }

    if (t < 128) {
        const int c = t * 4;
        const float* src = (c < ND_) ? (ga.x + ((size_t)b * NN + isrc) * ND_ + c)
                                     : (ga.x + ((size_t)b * NN + itgt) * ND_ + (c - ND_));
        const float4 vv = *(const float4*)src;
        ushort4 ov;
        ov.x = f2bf(vv.x); ov.y = f2bf(vv.y); ov.z = f2bf(vv.z); ov.w = f2bf(vv.w);
        *(ushort4*)(An + (size_t)r * 512 + c) = ov;
    } else if (t < 160) {
        const int c  = (t - 128) * 4;
        const float tt = (c < TD_) ? ga.ts[b * NN + isrc] : ga.ts[b * NN + itgt];
        const int  cb = (c < TD_) ? c : c - TD_;
        ushort4 ov;
        ov.x = f2bf(sinf(tt * ga.wtemb[cb + 0] + ga.btemb[cb + 0]));
        ov.y = f2bf(sinf(tt * ga.wtemb[cb + 1] + ga.btemb[cb + 1]));
        ov.z = f2bf(sinf(tt * ga.wtemb[cb + 2] + ga.btemb[cb + 2]));
        ov.w = f2bf(sinf(tt * ga.wtemb[cb + 3] + ga.btemb[cb + 3]));
        *(ushort4*)(Akv + (size_t)r * 256 + c) = ov;
    } else if (t < 192) {
        const int c = (t - 160) * 4;
        float4 vv = make_float4(0.f, 0.f, 0.f, 0.f);
        if (ge < EE) vv = *(const float4*)(ga.eattr + ((size_t)b * EE + ge) * ED_ + c);
        ushort4 ov;
        ov.x = f2bf(vv.x); ov.y = f2bf(vv.y); ov.z = f2bf(vv.z); ov.w = f2bf(vv.w);
        *(ushort4*)(Akv + (size_t)r * 256 + 128 + c) = ov;
    }
}

// ---------------------------------------------------------------------------
// Weight folding / conversion helpers
// ---------------------------------------------------------------------------
__global__ __launch_bounds__(256)
void comb_w_bf(const float* __restrict__ Wa, const float* __restrict__ Wb,
               u16* __restrict__ out, int Kin, int ostride)
{
    const int idx  = blockIdx.x * 256 + threadIdx.x;
    const int c    = idx / Kin;
    const int kcol = idx - c * Kin;
    float acc = 0.f;
    for (int j = 0; j < CC; j++)
        acc += Wa[c * CC + j] * Wb[j * Kin + kcol];
    out[(size_t)c * ostride + kcol] = f2bf(acc);
}

__global__ __launch_bounds__(256)
void comb_b(const float* __restrict__ Wa, const float* __restrict__ bin,
            const float* __restrict__ ba, float* __restrict__ bout)
{
    const int c = blockIdx.x * 256 + threadIdx.x;
    float acc = ba[c];
    for (int j = 0; j < CC; j++)
        acc += Wa[c * CC + j] * bin[j];
    bout[c] = acc;
}

__global__ __launch_bounds__(256)
void cvt_bf(const float* __restrict__ in, u16* __restrict__ out, int n)
{
    const int i = (blockIdx.x * 256 + threadIdx.x) * 4;
    if (i < n) {
        const float4 v = *(const float4*)(in + i);
        ushort4 ov;
        ov.x = f2bf(v.x); ov.y = f2bf(v.y); ov.z = f2bf(v.z); ov.w = f2bf(v.w);
        *(ushort4*)(out + i) = ov;
    }
}

__global__ __launch_bounds__(256)
void zero_u16(u16* __restrict__ p, int n)
{
    const int i = blockIdx.x * 256 + threadIdx.x;
    if (i < n) p[i] = 0;
}

__global__ __launch_bounds__(256)
void copy_f32(const float* __restrict__ in, float* __restrict__ out, int n)
{
    const int i = blockIdx.x * 256 + threadIdx.x;
    if (i < n) out[i] = in[i];
}

// ---------------------------------------------------------------------------
// Batch-axis attention, rows 4e..4e+3 adjacent. Block = 4 edges x 64 lanes.
// ---------------------------------------------------------------------------
__global__ __launch_bounds__(256)
void attn_kernel(const u16* __restrict__ nodq, const u16* __restrict__ kv,
                 u16* __restrict__ ctx)
{
    const int e    = blockIdx.x * 4 + (threadIdx.x >> 6);
    const int lane = threadIdx.x & 63;
    const int off  = (lane >> 3) * 64 + (lane & 7) * 8;   // u16 offset in row

    float qf[4][8], kf[4][8], vf[4][8];
    #pragma unroll
    for (int l = 0; l < 4; l++) {
        const size_t rq = (size_t)(4 * e + l) * 1024;
        const uint4 qv = *(const uint4*)(nodq + rq + 512 + off);
        const uint4 kx = *(const uint4*)(kv + rq + off);
        const uint4 vx = *(const uint4*)(kv + rq + 512 + off);
        const u32 qa[4] = {qv.x, qv.y, qv.z, qv.w};
        const u32 ka[4] = {kx.x, kx.y, kx.z, kx.w};
        const u32 va[4] = {vx.x, vx.y, vx.z, vx.w};
        #pragma unroll
        for (int p = 0; p < 4; p++) {
            qf[l][2*p] = bf2f((u16)qa[p]); qf[l][2*p+1] = bf2f((u16)(qa[p] >> 16));
            kf[l][2*p] = bf2f((u16)ka[p]); kf[l][2*p+1] = bf2f((u16)(ka[p] >> 16));
            vf[l][2*p] = bf2f((u16)va[p]); vf[l][2*p+1] = bf2f((u16)(va[p] >> 16));
        }
    }

    float sc[4][4];
    #pragma unroll
    for (int l = 0; l < 4; l++) {
        #pragma unroll
        for (int m = 0; m < 4; m++) {
            float p = 0.f;
            #pragma unroll
            for (int d = 0; d < 8; d++) p += qf[l][d] * kf[m][d];
            p += __shfl_xor(p, 1, 64);
            p += __shfl_xor(p, 2, 64);
            p += __shfl_xor(p, 4, 64);
            sc[l][m] = p * 0.125f;
        }
    }

    #pragma unroll
    for (int l = 0; l < 4; l++) {
        const float mx = fmaxf(fmaxf(sc[l][0], sc[l][1]), fmaxf(sc[l][2], sc[l][3]));
        float a[4], s = 0.f;
        #pragma unroll
        for (int m = 0; m < 4; m++) { a[m] = __expf(sc[l][m] - mx); s += a[m]; }
        const float inv = 1.0f / s;
        float cv[8];
        #pragma unroll
        for (int d = 0; d < 8; d++) {
            cv[d] = (a[0] * vf[0][d] + a[1] * vf[1][d] +
                     a[2] * vf[2][d] + a[3] * vf[3][d]) * inv;
        }
        ushort4 o0, o1;
        o0.x = f2bf(cv[0]); o0.y = f2bf(cv[1]); o0.z = f2bf(cv[2]); o0.w = f2bf(cv[3]);
        o1.x = f2bf(cv[4]); o1.y = f2bf(cv[5]); o1.z = f2bf(cv[6]); o1.w = f2bf(cv[7]);
        u16* crow = ctx + (size_t)(4 * e + l) * 512 + off;
        *(ushort4*)crow       = o0;
        *(ushort4*)(crow + 4) = o1;
    }
}

// ---------------------------------------------------------------------------
// ln1: out1 = LN(nodef + attn_out) -> bf16 only (256 thr, 2 cols/thread)
// ---------------------------------------------------------------------------
__global__ __launch_bounds__(256)
void ln1_kernel(const u16* __restrict__ nodq, const u16* __restrict__ aout,
                const float* __restrict__ g, const float* __restrict__ be,
                u16* __restrict__ outb)
{
    const int r = blockIdx.x;
    const int t = threadIdx.x;
    const int c = t * 2;

    const u32 nf = *(const u32*)(nodq + (size_t)r * 1024 + c);
    const u32 ao = *(const u32*)(aout + (size_t)r * 512 + c);
    const float v0 = bf2f((u16)nf) + bf2f((u16)ao);
    const float v1 = bf2f((u16)(nf >> 16)) + bf2f((u16)(ao >> 16));

    __shared__ float red[4];
    float s = v0 + v1;
    #pragma unroll
    for (int o = 32; o; o >>= 1) s += __shfl_xor(s, o, 64);
    const int wid = t >> 6, lane = t & 63;
    if (lane == 0) red[wid] = s;
    __syncthreads();
    const float mean = (red[0] + red[1] + red[2] + red[3]) * (1.0f / 512.0f);

    const float d0 = v0 - mean, d1 = v1 - mean;
    float vs = d0 * d0 + d1 * d1;
    #pragma unroll
    for (int o = 32; o; o >>= 1) vs += __shfl_xor(vs, o, 64);
    __syncthreads();
    if (lane == 0) red[wid] = vs;
    __syncthreads();
    const float var = (red[0] + red[1] + red[2] + red[3]) * (1.0f / 512.0f);
    const float rstd = rsqrtf(var + 1e-5f);

    const float y0 = d0 * rstd * g[c]     + be[c];
    const float y1 = d1 * rstd * g[c + 1] + be[c + 1];
    ushort2 ov; ov.x = f2bf(y0); ov.y = f2bf(y1);
    *(ushort2*)(outb + (size_t)r * 512 + c) = ov;
}

// ---------------------------------------------------------------------------
// ln2: d_out[grow] = LN(out1 + ffn) (f32 out; sole writer of d_out)
// ---------------------------------------------------------------------------
__global__ __launch_bounds__(256)
void ln2_kernel(const u16* __restrict__ out1, const u16* __restrict__ ffn,
                const float* __restrict__ g, const float* __restrict__ be,
                float* __restrict__ out, int e0)
{
    const int r = blockIdx.x;
    const int t = threadIdx.x;
    const int c = t * 2;

    const u32 o1 = *(const u32*)(out1 + (size_t)r * 512 + c);
    const u32 ff = *(const u32*)(ffn  + (size_t)r * 512 + c);
    const float v0 = bf2f((u16)o1) + bf2f((u16)ff);
    const float v1 = bf2f((u16)(o1 >> 16)) + bf2f((u16)(ff >> 16));

    __shared__ float red[4];
    float s = v0 + v1;
    #pragma unroll
    for (int o = 32; o; o >>= 1) s += __shfl_xor(s, o, 64);
    const int wid = t >> 6, lane = t & 63;
    if (lane == 0) red[wid] = s;
    __syncthreads();
    const float mean = (red[0] + red[1] + red[2] + red[3]) * (1.0f / 512.0f);

    const float d0 = v0 - mean, d1 = v1 - mean;
    float vs = d0 * d0 + d1 * d1;
    #pragma unroll
    for (int o = 32; o; o >>= 1) vs += __shfl_xor(vs, o, 64);
    __syncthreads();
    if (lane == 0) red[wid] = vs;
    __syncthreads();
    const float var = (red[0] + red[1] + red[2] + red[3]) * (1.0f / 512.0f);
    const float rstd = rsqrtf(var + 1e-5f);

    const int el = r >> 2;
    const int b  = r & 3;
    float2 ov;
    ov.x = d0 * rstd * g[c]     + be[c];
    ov.y = d1 * rstd * g[c + 1] + be[c + 1];
    *(float2*)(out + ((size_t)b * LL + e0 + el) * CC + c) = ov;
}

// ---------------------------------------------------------------------------
extern "C" void kernel_launch(void* const* d_in, const int* in_sizes, int n_in,
                              void* d_out, int out_size, void* d_ws, size_t ws_size,
                              hipStream_t stream)
{
    const float* x       = (const float*)d_in[0];
    const float* eattr   = (const float*)d_in[1];
    const float* ts      = (const float*)d_in[2];
    const float* W_node  = (const float*)d_in[3];
    const float* b_node  = (const float*)d_in[4];
    const float* W_temb  = (const float*)d_in[5];
    const float* b_temb  = (const float*)d_in[6];
    const float* W_timef = (const float*)d_in[7];
    const float* b_timef = (const float*)d_in[8];
    const float* W_edge  = (const float*)d_in[9];
    const float* b_edge  = (const float*)d_in[10];
    const float* Wq      = (const float*)d_in[11];
    const float* bq      = (const float*)d_in[12];
    const float* Wk      = (const float*)d_in[13];
    const float* bk      = (const float*)d_in[14];
    const float* Wv      = (const float*)d_in[15];
    const float* bv      = (const float*)d_in[16];
    const float* Wo      = (const float*)d_in[17];
    const float* bo      = (const float*)d_in[18];
    const float* W1      = (const float*)d_in[19];
    const float* b1      = (const float*)d_in[20];
    const float* W2      = (const float*)d_in[21];
    const float* b2      = (const float*)d_in[22];
    const float* g1      = (const float*)d_in[23];
    const float* be1     = (const float*)d_in[24];
    const float* g2      = (const float*)d_in[25];
    const float* be2     = (const float*)d_in[26];
    const int*   ei      = (const int*)d_in[27];

    float* out = (float*)d_out;

    // ---- weight region (bf16) at front of ws ----
    u16* wnq_cat = (u16*)d_ws;              // 1024x512  [W_node ; Wq@W_node]
    u16* wkv_cat = wnq_cat + 524288;        // 1024x256  block-diag [Wk@W_timef | Wv@W_edge]
    u16* wo      = wkv_cat + 262144;        // 512x512
    u16* w1b     = wo + 262144;             // 2048x512
    u16* w2b     = w1b + 1048576;           // 512x2048
    float* bias_nq = (float*)(w2b + 1048576);   // 1024
    float* bias_kv = bias_nq + 1024;            // 1024
    char*  cbase   = (char*)(bias_kv + 1024);
    const size_t fixedB = (size_t)(cbase - (char*)d_ws);

    // ---- chunk sizing: per edge = 4 rows x 4096 u16 = 32768 B ----
    const size_t availB = (ws_size > fixedB) ? (ws_size - fixedB) : 0;
    int Ec = (int)(availB / 32768);
    Ec = (Ec / 64) * 64;                    // rows multiple of 256
    if (Ec > LL) Ec = LL;
    if (Ec < 64) Ec = 64;

    const size_t rmax = (size_t)4 * Ec;
    u16* An   = (u16*)cbase;                // rows x 512  (A_node -> ctx -> out1)
    u16* nodq = An + rmax * 512;            // rows x 1024 [nodef | q]
    u16* R    = nodq + rmax * 1024;         // rows x 2048 overlay
    u16* Akv  = R;                          // rows x 256
    u16* kv   = R + rmax * 256;             // rows x 1024 [k | v]
    u16* hid  = R;                          // rows x 2048 (Akv,kv dead by then)
    u16* aout = R + rmax * 2048;            // rows x 512  attn_out -> ffn

    GatherArgs ga{x, ts, W_temb, b_temb, eattr, ei};
    const dim3 blk(256);
    const dim3 gblk(512);

    // ---- weight prep ----
    cvt_bf   <<<dim3(256),  blk, 0, stream>>>(W_node, wnq_cat, 262144);
    comb_w_bf<<<dim3(1024), blk, 0, stream>>>(Wq, W_node, wnq_cat + 262144, 512, 512);
    zero_u16 <<<dim3(1024), blk, 0, stream>>>(wkv_cat, 262144);
    comb_w_bf<<<dim3(256),  blk, 0, stream>>>(Wk, W_timef, wkv_cat, 128, 256);
    comb_w_bf<<<dim3(256),  blk, 0, stream>>>(Wv, W_edge, wkv_cat + 512 * 256 + 128, 128, 256);
    cvt_bf   <<<dim3(256),  blk, 0, stream>>>(Wo, wo,  262144);
    cvt_bf   <<<dim3(1024), blk, 0, stream>>>(W1, w1b, 1048576);
    cvt_bf   <<<dim3(1024), blk, 0, stream>>>(W2, w2b, 1048576);
    copy_f32 <<<dim3(2),    blk, 0, stream>>>(b_node, bias_nq, 512);
    comb_b   <<<dim3(2),    blk, 0, stream>>>(Wq, b_node,  bq, bias_nq + 512);
    comb_b   <<<dim3(2),    blk, 0, stream>>>(Wk, b_timef, bk, bias_kv);
    comb_b   <<<dim3(2),    blk, 0, stream>>>(Wv, b_edge,  bv, bias_kv + 512);

    for (int e0 = 0; e0 < LL; e0 += Ec) {
        int ec = LL - e0; if (ec > Ec) ec = Ec;
        const int rows = 4 * ec;
        const int gy = rows / 256;

        prep_kernel<<<dim3(rows), blk, 0, stream>>>(An, Akv, e0, ga);

        // [nodef|q] = An @ wnq_cat^T ; [k|v] = Akv @ wkv_cat^T
        gemm_mfma<false><<<dim3(4, gy), gblk, 0, stream>>>(An,  wnq_cat, bias_nq, nodq, 1024, 512);
        gemm_mfma<false><<<dim3(4, gy), gblk, 0, stream>>>(Akv, wkv_cat, bias_kv, kv,   1024, 256);

        attn_kernel<<<dim3(ec / 4), blk, 0, stream>>>(nodq, kv, An /*ctx*/);

        // attn_out = ctx @ Wo^T + bo ; out1 = LN(nodef + attn_out) -> An (bf16)
        gemm_mfma<false><<<dim3(2, gy), gblk, 0, stream>>>(An, wo, bo, aout, 512, 512);
        ln1_kernel<<<dim3(rows), blk, 0, stream>>>(nodq, aout, g1, be1, An /*out1*/);

        // FFN: hid = gelu(out1 @ W1^T) ; ffn = hid @ W2^T -> aout
        gemm_mfma<true ><<<dim3(8, gy), gblk, 0, stream>>>(An,  w1b, b1, hid, 2048, 512);
        gemm_mfma<false><<<dim3(2, gy), gblk, 0, stream>>>(hid, w2b, b2, aout /*ffn*/, 512, 2048);

        ln2_kernel<<<dim3(rows), blk, 0, stream>>>(An, aout, g2, be2, out, e0);
    }
}

// Round 10
// 1328.914 us; speedup vs baseline: 1.4382x; 1.0555x over previous
//
#include <hip/hip_runtime.h>
#include <math.h>

#define BB 4
#define NN 2048
#define EE 16384
#define LL (EE + NN)      // 18432
#define ND_ 256
#define ED_ 128
#define TD_ 64
#define CC 512
#define HH 8
#define DH_ 64
#define C4 2048

typedef unsigned short u16;
typedef unsigned int u32;
typedef __bf16 bhalf8 __attribute__((ext_vector_type(8)));
typedef float f32x4 __attribute__((ext_vector_type(4)));

struct GatherArgs {
    const float* x;      // (B,N,ND)
    const float* ts;     // (B,N)
    const float* wtemb;  // (TD)
    const float* btemb;  // (TD)
    const float* eattr;  // (B,E,ED)
    const int*   ei;     // (B,2,E)
};

__device__ __forceinline__ u16 f2bf(float f) {
    union { float f; unsigned u; } c; c.f = f;
    const unsigned r = (c.u + 0x7fffu + ((c.u >> 16) & 1u)) >> 16;   // RNE
    return (u16)r;
}
__device__ __forceinline__ u16 f2bf_hw(float f) {      // native cvt (RNE)
    __bf16 h = (__bf16)f;
    union { __bf16 h; u16 u; } c; c.h = h; return c.u;
}
__device__ __forceinline__ float bf2f(u16 u) {
    union { unsigned u; float f; } c; c.u = ((unsigned)u) << 16; return c.f;
}
// tanh-form GELU: |err vs exact-erf gelu| ~3e-4, far below bf16 rounding
__device__ __forceinline__ float gelu_fast(float v) {
    const float u = v * (0.7978845608f + 0.0356774081f * v * v);
    const float e = __expf(2.0f * u);
    const float t = 1.0f - 2.0f / (e + 1.0f);
    return 0.5f * v * (1.0f + t);
}

#define GLD16(gp, lp) __builtin_amdgcn_global_load_lds( \
    (const __attribute__((address_space(1))) unsigned int*)(gp), \
    (__attribute__((address_space(3))) unsigned int*)(lp), 16, 0, 0)

// ---------------------------------------------------------------------------
// bf16 MFMA GEMM — 8-phase-per-2-tiles schedule (T2+T3+T4+T5, m201 template):
//   Y[M x N](bf16) = A[M x K] @ W[N x K]^T + bias(f32)
// 256x256 block, 512 thr = 8 waves (2M x 4N), per-wave 128x64 output.
// BK=64, double-buffered 128 KB LDS. Per K-tile 4 phases, each:
//   {ds_read subtile || stage ONE half-tile (2xGLD16)} -> barrier ->
//   lgkmcnt(0) -> setprio(1) -> 16 MFMA -> setprio(0) -> barrier
// Staging staggered by liveness: A[t+1] halves at ph1/ph2 (opposite buffer),
// B[t+2] halves at ph3/ph4 (same buffer, B[t] dead after ph2). One
// s_waitcnt vmcnt(4) per tile at ph4 — never drains to 0 in steady state.
// LDS swizzle (T2): chunk c of row r stored at c^(r&7); inverse-swizzled
// global source, XOR on ds_read (rule #21). 0 bank conflicts (round-7 PMC).
// M%256==0, N%256==0, K%64==0, K>=128.
// ---------------------------------------------------------------------------
template<bool GELU>
__global__ __launch_bounds__(512, 2)
void gemm_mfma(const u16* __restrict__ A, const u16* __restrict__ W,
               const float* __restrict__ bias, u16* __restrict__ Y,
               int N, int K)
{
    __shared__ u16 As[2][16384];   // 256 rows x 64 bf16 per buffer (64 KB)
    __shared__ u16 Bs[2][16384];   // 64 KB

    // bijective XCD-chunked swizzle (m204)
    const int o    = blockIdx.y * gridDim.x + blockIdx.x;
    const int nwg  = gridDim.x * gridDim.y;
    const int xcd  = o & 7;
    const int qq   = nwg >> 3, rr = nwg & 7;
    const int wg   = (xcd < rr ? xcd * (qq + 1) : rr * (qq + 1) + (xcd - rr) * qq) + (o >> 3);
    const int bx   = wg % gridDim.x;
    const int by   = wg / gridDim.x;
    const int m0   = by * 256;
    const int n0   = bx * 256;

    const int tid  = threadIdx.x;
    const int lane = tid & 63;
    const int wid  = tid >> 6;          // 0..7
    const int wm   = wid >> 2;          // wave row: 2 x 128 rows
    const int wn   = wid & 3;           // wave col: 4 x 64 cols

    // staging: thread t covers LDS row t>>3 (+64 per half-step), chunk t&7.
    // inverse-swizzled global column chunk: (t&7) ^ ((t>>3)&7)
    const int swz8 = (((tid & 7) ^ ((tid >> 3) & 7))) * 8;
    const size_t sK = (size_t)K;
    const u16* Agb = A + (size_t)(m0 + (tid >> 3)) * sK + swz8;
    const u16* Wgb = W + (size_t)(n0 + (tid >> 3)) * sK + swz8;

    const int NT  = K >> 6;             // K-tiles of 64
    const int rlo = lane & 15;
    const int hi4 = lane >> 4;          // 0..3
    const int lk  = lane & 7;           // read-side XOR key (== row&7)

// half h of tile kt: rows h*128 .. h*128+127 -> LDS [h*8192 .. h*8192+8191]
#define STAGE_A(kt, h) do {                                      \
    const u16* _g = Agb + (size_t)(kt) * 64 + (size_t)(h) * 128 * sK; \
    u16* _l = &As[(kt) & 1][(h) * 8192 + tid * 8];               \
    GLD16(_g,           _l);                                     \
    GLD16(_g + 64 * sK, _l + 4096);                              \
} while (0)
#define STAGE_B(kt, h) do {                                      \
    const u16* _g = Wgb + (size_t)(kt) * 64 + (size_t)(h) * 128 * sK; \
    u16* _l = &Bs[(kt) & 1][(h) * 8192 + tid * 8];               \
    GLD16(_g,           _l);                                     \
    GLD16(_g + 64 * sK, _l + 4096);                              \
} while (0)

#define SWZOFF(ks) (((((ks) << 2) | hi4) ^ lk) << 3)
#define RD(buf, row, ks) (*(const bhalf8*)&(buf)[(row) * 64 + SWZOFF(ks)])

#define PHASE_SYNC() do {                                        \
    __builtin_amdgcn_sched_barrier(0);                           \
    __builtin_amdgcn_s_barrier();                                \
    asm volatile("s_waitcnt lgkmcnt(0)" ::: "memory");           \
    __builtin_amdgcn_sched_barrier(0);                           \
} while (0)
#define PHASE_END() do {                                         \
    __builtin_amdgcn_sched_barrier(0);                           \
    __builtin_amdgcn_s_barrier();                                \
    __builtin_amdgcn_sched_barrier(0);                           \
} while (0)

    f32x4 acc[8][4] = {};

    // prologue: tile0 fully + B halves of tile1 (A[1] staged in t=0 ph1/ph2)
    STAGE_A(0, 0); STAGE_A(0, 1);
    STAGE_B(0, 0); STAGE_B(0, 1);
    STAGE_B(1, 0); STAGE_B(1, 1);
    asm volatile("s_waitcnt vmcnt(4)" ::: "memory");   // tile0's 8 loads done
    __builtin_amdgcn_s_barrier();
    __builtin_amdgcn_sched_barrier(0);

    for (int t = 0; t < NT; ++t) {
        const u16* as = &As[t & 1][0];
        const u16* bs = &Bs[t & 1][0];
        bhalf8 aLo[4][2], aHi[4][2], b0[2][2], b1[2][2];

        // ---- phase 1: read aLo + b0 ; stage A0[t+1] ; MFMA q(0,0) ----
        #pragma unroll
        for (int i = 0; i < 4; ++i) {
            aLo[i][0] = RD(as, wm * 128 + i * 16 + rlo, 0);
            aLo[i][1] = RD(as, wm * 128 + i * 16 + rlo, 1);
        }
        #pragma unroll
        for (int j = 0; j < 2; ++j) {
            b0[j][0] = RD(bs, wn * 64 + j * 16 + rlo, 0);
            b0[j][1] = RD(bs, wn * 64 + j * 16 + rlo, 1);
        }
        if (t + 1 < NT) STAGE_A(t + 1, 0);
        PHASE_SYNC();
        __builtin_amdgcn_s_setprio(1);
        #pragma unroll
        for (int i = 0; i < 4; ++i)
            #pragma unroll
            for (int j = 0; j < 2; ++j)
                #pragma unroll
                for (int ks = 0; ks < 2; ++ks)
                    acc[i][j] = __builtin_amdgcn_mfma_f32_16x16x32_bf16(b0[j][ks], aLo[i][ks], acc[i][j], 0, 0, 0);
        __builtin_amdgcn_s_setprio(0);
        PHASE_END();

        // ---- phase 2: read b1 ; stage A1[t+1] ; MFMA q(0,1) ----
        #pragma unroll
        for (int j = 0; j < 2; ++j) {
            b1[j][0] = RD(bs, wn * 64 + 32 + j * 16 + rlo, 0);
            b1[j][1] = RD(bs, wn * 64 + 32 + j * 16 + rlo, 1);
        }
        if (t + 1 < NT) STAGE_A(t + 1, 1);
        PHASE_SYNC();
        __builtin_amdgcn_s_setprio(1);
        #pragma unroll
        for (int i = 0; i < 4; ++i)
            #pragma unroll
            for (int j = 0; j < 2; ++j)
                #pragma unroll
                for (int ks = 0; ks < 2; ++ks)
                    acc[i][2 + j] = __builtin_amdgcn_mfma_f32_16x16x32_bf16(b1[j][ks], aLo[i][ks], acc[i][2 + j], 0, 0, 0);
        __builtin_amdgcn_s_setprio(0);
        PHASE_END();

        // ---- phase 3: read aHi ; stage B0[t+2] ; MFMA q(1,0) ----
        #pragma unroll
        for (int i = 0; i < 4; ++i) {
            aHi[i][0] = RD(as, wm * 128 + 64 + i * 16 + rlo, 0);
            aHi[i][1] = RD(as, wm * 128 + 64 + i * 16 + rlo, 1);
        }
        if (t + 2 < NT) STAGE_B(t + 2, 0);
        PHASE_SYNC();
        __builtin_amdgcn_s_setprio(1);
        #pragma unroll
        for (int i = 0; i < 4; ++i)
            #pragma unroll
            for (int j = 0; j < 2; ++j)
                #pragma unroll
                for (int ks = 0; ks < 2; ++ks)
                    acc[4 + i][j] = __builtin_amdgcn_mfma_f32_16x16x32_bf16(b0[j][ks], aHi[i][ks], acc[4 + i][j], 0, 0, 0);
        __builtin_amdgcn_s_setprio(0);
        PHASE_END();

        // ---- phase 4: stage B1[t+2] ; counted vmcnt ; MFMA q(1,1) ----
        if (t + 2 < NT) {
            STAGE_B(t + 2, 1);
            asm volatile("s_waitcnt vmcnt(4)" ::: "memory");  // A[t+1]+older done
        } else if (t < NT - 1) {
            asm volatile("s_waitcnt vmcnt(0)" ::: "memory");  // tail drain
        }
        PHASE_SYNC();
        __builtin_amdgcn_s_setprio(1);
        #pragma unroll
        for (int i = 0; i < 4; ++i)
            #pragma unroll
            for (int j = 0; j < 2; ++j)
                #pragma unroll
                for (int ks = 0; ks < 2; ++ks)
                    acc[4 + i][2 + j] = __builtin_amdgcn_mfma_f32_16x16x32_bf16(b1[j][ks], aHi[i][ks], acc[4 + i][2 + j], 0, 0, 0);
        __builtin_amdgcn_s_setprio(0);
        if (t < NT - 1) PHASE_END();
    }
#undef STAGE_A
#undef STAGE_B
#undef SWZOFF
#undef RD
#undef PHASE_SYNC
#undef PHASE_END

    // Epilogue: row = m0+wm*128+i*16+(lane&15); cols = n0+wn*64+j*16+(lane>>4)*4
    const int row0 = m0 + wm * 128;
    const int col0 = n0 + wn * 64;
    const int rq   = (lane >> 4) * 4;
    float4 bi[4];
    #pragma unroll
    for (int j = 0; j < 4; ++j)
        bi[j] = *(const float4*)(bias + col0 + j * 16 + rq);

    #pragma unroll
    for (int i = 0; i < 8; ++i) {
        const int gr = row0 + i * 16 + rlo;
        u16* yrow = Y + (size_t)gr * N + col0;
        #pragma unroll
        for (int j = 0; j < 4; ++j) {
            float v0 = acc[i][j][0] + bi[j].x;
            float v1 = acc[i][j][1] + bi[j].y;
            float v2 = acc[i][j][2] + bi[j].z;
            float v3 = acc[i][j][3] + bi[j].w;
            if constexpr (GELU) {
                v0 = gelu_fast(v0); v1 = gelu_fast(v1);
                v2 = gelu_fast(v2); v3 = gelu_fast(v3);
            }
            ushort4 ov;
            ov.x = f2bf_hw(v0); ov.y = f2bf_hw(v1);
            ov.z = f2bf_hw(v2); ov.w = f2bf_hw(v3);
            *(ushort4*)(yrow + j * 16 + rq) = ov;
        }
    }
}

// ---------------------------------------------------------------------------
// Prep: row order r = 4*edge_local + batch. Builds bf16 A_node (rows x 512)
// and A_kv = [time|edge] (rows x 256).
// ---------------------------------------------------------------------------
__global__ __launch_bounds__(256)
void prep_kernel(u16* __restrict__ An, u16* __restrict__ Akv,
                 int e0, GatherArgs ga)
{
    const int r  = blockIdx.x;
    const int el = r >> 2;
    const int b  = r & 3;
    const int ge = e0 + el;
    const int t  = threadIdx.x;

    int isrc, itgt;
    if (ge < EE) {
        isrc = ga.ei[(b * 2 + 0) * EE + ge];
        itgt = ga.ei[(b * 2 + 1) * EE + ge];
    } else {
        isrc = itgt = ge - EE;
    }

    if (t < 128) {
        const int c = t * 4;
        const float* src = (c < ND_) ? (ga.x + ((size_t)b * NN + isrc) * ND_ + c)
                                     : (ga.x + ((size_t)b * NN + itgt) * ND_ + (c - ND_));
        const float4 vv = *(const float4*)src;
        ushort4 ov;
        ov.x = f2bf(vv.x); ov.y = f2bf(vv.y); ov.z = f2bf(vv.z); ov.w = f2bf(vv.w);
        *(ushort4*)(An + (size_t)r * 512 + c) = ov;
    } else if (t < 160) {
        const int c  = (t - 128) * 4;
        const float tt = (c < TD_) ? ga.ts[b * NN + isrc] : ga.ts[b * NN + itgt];
        const int  cb = (c < TD_) ? c : c - TD_;
        ushort4 ov;
        ov.x = f2bf(sinf(tt * ga.wtemb[cb + 0] + ga.btemb[cb + 0]));
        ov.y = f2bf(sinf(tt * ga.wtemb[cb + 1] + ga.btemb[cb + 1]));
        ov.z = f2bf(sinf(tt * ga.wtemb[cb + 2] + ga.btemb[cb + 2]));
        ov.w = f2bf(sinf(tt * ga.wtemb[cb + 3] + ga.btemb[cb + 3]));
        *(ushort4*)(Akv + (size_t)r * 256 + c) = ov;
    } else if (t < 192) {
        const int c = (t - 160) * 4;
        float4 vv = make_float4(0.f, 0.f, 0.f, 0.f);
        if (ge < EE) vv = *(const float4*)(ga.eattr + ((size_t)b * EE + ge) * ED_ + c);
        ushort4 ov;
        ov.x = f2bf(vv.x); ov.y = f2bf(vv.y); ov.z = f2bf(vv.z); ov.w = f2bf(vv.w);
        *(ushort4*)(Akv + (size_t)r * 256 + 128 + c) = ov;
    }
}

// ---------------------------------------------------------------------------
// Weight folding / conversion helpers
// ---------------------------------------------------------------------------
__global__ __launch_bounds__(256)
void comb_w_bf(const float* __restrict__ Wa, const float* __restrict__ Wb,
               u16* __restrict__ out, int Kin, int ostride)
{
    const int idx  = blockIdx.x * 256 + threadIdx.x;
    const int c    = idx / Kin;
    const int kcol = idx - c * Kin;
    float acc = 0.f;
    for (int j = 0; j < CC; j++)
        acc += Wa[c * CC + j] * Wb[j * Kin + kcol];
    out[(size_t)c * ostride + kcol] = f2bf(acc);
}

__global__ __launch_bounds__(256)
void comb_b(const float* __restrict__ Wa, const float* __restrict__ bin,
            const float* __restrict__ ba, float* __restrict__ bout)
{
    const int c = blockIdx.x * 256 + threadIdx.x;
    float acc = ba[c];
    for (int j = 0; j < CC; j++)
        acc += Wa[c * CC + j] * bin[j];
    bout[c] = acc;
}

__global__ __launch_bounds__(256)
void cvt_bf(const float* __restrict__ in, u16* __restrict__ out, int n)
{
    const int i = (blockIdx.x * 256 + threadIdx.x) * 4;
    if (i < n) {
        const float4 v = *(const float4*)(in + i);
        ushort4 ov;
        ov.x = f2bf(v.x); ov.y = f2bf(v.y); ov.z = f2bf(v.z); ov.w = f2bf(v.w);
        *(ushort4*)(out + i) = ov;
    }
}

__global__ __launch_bounds__(256)
void zero_u16(u16* __restrict__ p, int n)
{
    const int i = blockIdx.x * 256 + threadIdx.x;
    if (i < n) p[i] = 0;
}

__global__ __launch_bounds__(256)
void copy_f32(const float* __restrict__ in, float* __restrict__ out, int n)
{
    const int i = blockIdx.x * 256 + threadIdx.x;
    if (i < n) out[i] = in[i];
}

// ---------------------------------------------------------------------------
// Batch-axis attention, rows 4e..4e+3 adjacent. Block = 4 edges x 64 lanes.
// ---------------------------------------------------------------------------
__global__ __launch_bounds__(256)
void attn_kernel(const u16* __restrict__ nodq, const u16* __restrict__ kv,
                 u16* __restrict__ ctx)
{
    const int e    = blockIdx.x * 4 + (threadIdx.x >> 6);
    const int lane = threadIdx.x & 63;
    const int off  = (lane >> 3) * 64 + (lane & 7) * 8;   // u16 offset in row

    float qf[4][8], kf[4][8], vf[4][8];
    #pragma unroll
    for (int l = 0; l < 4; l++) {
        const size_t rq = (size_t)(4 * e + l) * 1024;
        const uint4 qv = *(const uint4*)(nodq + rq + 512 + off);
        const uint4 kx = *(const uint4*)(kv + rq + off);
        const uint4 vx = *(const uint4*)(kv + rq + 512 + off);
        const u32 qa[4] = {qv.x, qv.y, qv.z, qv.w};
        const u32 ka[4] = {kx.x, kx.y, kx.z, kx.w};
        const u32 va[4] = {vx.x, vx.y, vx.z, vx.w};
        #pragma unroll
        for (int p = 0; p < 4; p++) {
            qf[l][2*p] = bf2f((u16)qa[p]); qf[l][2*p+1] = bf2f((u16)(qa[p] >> 16));
            kf[l][2*p] = bf2f((u16)ka[p]); kf[l][2*p+1] = bf2f((u16)(ka[p] >> 16));
            vf[l][2*p] = bf2f((u16)va[p]); vf[l][2*p+1] = bf2f((u16)(va[p] >> 16));
        }
    }

    float sc[4][4];
    #pragma unroll
    for (int l = 0; l < 4; l++) {
        #pragma unroll
        for (int m = 0; m < 4; m++) {
            float p = 0.f;
            #pragma unroll
            for (int d = 0; d < 8; d++) p += qf[l][d] * kf[m][d];
            p += __shfl_xor(p, 1, 64);
            p += __shfl_xor(p, 2, 64);
            p += __shfl_xor(p, 4, 64);
            sc[l][m] = p * 0.125f;
        }
    }

    #pragma unroll
    for (int l = 0; l < 4; l++) {
        const float mx = fmaxf(fmaxf(sc[l][0], sc[l][1]), fmaxf(sc[l][2], sc[l][3]));
        float a[4], s = 0.f;
        #pragma unroll
        for (int m = 0; m < 4; m++) { a[m] = __expf(sc[l][m] - mx); s += a[m]; }
        const float inv = 1.0f / s;
        float cv[8];
        #pragma unroll
        for (int d = 0; d < 8; d++) {
            cv[d] = (a[0] * vf[0][d] + a[1] * vf[1][d] +
                     a[2] * vf[2][d] + a[3] * vf[3][d]) * inv;
        }
        ushort4 o0, o1;
        o0.x = f2bf(cv[0]); o0.y = f2bf(cv[1]); o0.z = f2bf(cv[2]); o0.w = f2bf(cv[3]);
        o1.x = f2bf(cv[4]); o1.y = f2bf(cv[5]); o1.z = f2bf(cv[6]); o1.w = f2bf(cv[7]);
        u16* crow = ctx + (size_t)(4 * e + l) * 512 + off;
        *(ushort4*)crow       = o0;
        *(ushort4*)(crow + 4) = o1;
    }
}

// ---------------------------------------------------------------------------
// ln1 (wave-per-row): out1 = LN(nodef + attn_out) -> bf16.
// 4 waves/block = 4 rows; lane l covers cols 8l..8l+7 (one uint4 per input).
// Pure-shuffle reduce — no LDS, no __syncthreads (G13 / m146 lever).
// ---------------------------------------------------------------------------
__global__ __launch_bounds__(256)
void ln1_kernel(const u16* __restrict__ nodq, const u16* __restrict__ aout,
                const float* __restrict__ g, const float* __restrict__ be,
                u16* __restrict__ outb)
{
    const int r    = blockIdx.x * 4 + (threadIdx.x >> 6);
    const int lane = threadIdx.x & 63;
    const int c    = lane * 8;

    const uint4 nf = *(const uint4*)(nodq + (size_t)r * 1024 + c);
    const uint4 ao = *(const uint4*)(aout + (size_t)r * 512 + c);
    const u32 na[4] = {nf.x, nf.y, nf.z, nf.w};
    const u32 aa[4] = {ao.x, ao.y, ao.z, ao.w};

    float v[8];
    #pragma unroll
    for (int p = 0; p < 4; p++) {
        v[2*p]   = bf2f((u16)na[p])         + bf2f((u16)aa[p]);
        v[2*p+1] = bf2f((u16)(na[p] >> 16)) + bf2f((u16)(aa[p] >> 16));
    }

    float s = 0.f;
    #pragma unroll
    for (int p = 0; p < 8; p++) s += v[p];
    #pragma unroll
    for (int o = 32; o; o >>= 1) s += __shfl_xor(s, o, 64);
    const float mean = s * (1.0f / 512.0f);

    float d[8], vs = 0.f;
    #pragma unroll
    for (int p = 0; p < 8; p++) { d[p] = v[p] - mean; vs += d[p] * d[p]; }
    #pragma unroll
    for (int o = 32; o; o >>= 1) vs += __shfl_xor(vs, o, 64);
    const float rstd = rsqrtf(vs * (1.0f / 512.0f) + 1e-5f);

    const float4 g0 = *(const float4*)(g + c),  g1 = *(const float4*)(g + c + 4);
    const float4 b0 = *(const float4*)(be + c), b1 = *(const float4*)(be + c + 4);
    const float gg[8] = {g0.x, g0.y, g0.z, g0.w, g1.x, g1.y, g1.z, g1.w};
    const float bb[8] = {b0.x, b0.y, b0.z, b0.w, b1.x, b1.y, b1.z, b1.w};

    uint4 ov;
    u32 w[4];
    #pragma unroll
    for (int p = 0; p < 4; p++) {
        const float y0 = d[2*p]   * rstd * gg[2*p]   + bb[2*p];
        const float y1 = d[2*p+1] * rstd * gg[2*p+1] + bb[2*p+1];
        w[p] = (u32)f2bf(y0) | ((u32)f2bf(y1) << 16);
    }
    ov.x = w[0]; ov.y = w[1]; ov.z = w[2]; ov.w = w[3];
    *(uint4*)(outb + (size_t)r * 512 + c) = ov;
}

// ---------------------------------------------------------------------------
// ln2 (wave-per-row): d_out[grow] = LN(out1 + ffn), f32 out (sole d_out
// writer). Same wave-per-row layout; writes 2x float4 per lane.
// ---------------------------------------------------------------------------
__global__ __launch_bounds__(256)
void ln2_kernel(const u16* __restrict__ out1, const u16* __restrict__ ffn,
                const float* __restrict__ g, const float* __restrict__ be,
                float* __restrict__ out, int e0)
{
    const int r    = blockIdx.x * 4 + (threadIdx.x >> 6);
    const int lane = threadIdx.x & 63;
    const int c    = lane * 8;

    const uint4 o1 = *(const uint4*)(out1 + (size_t)r * 512 + c);
    const uint4 ff = *(const uint4*)(ffn  + (size_t)r * 512 + c);
    const u32 oa[4] = {o1.x, o1.y, o1.z, o1.w};
    const u32 fa[4] = {ff.x, ff.y, ff.z, ff.w};

    float v[8];
    #pragma unroll
    for (int p = 0; p < 4; p++) {
        v[2*p]   = bf2f((u16)oa[p])         + bf2f((u16)fa[p]);
        v[2*p+1] = bf2f((u16)(oa[p] >> 16)) + bf2f((u16)(fa[p] >> 16));
    }

    float s = 0.f;
    #pragma unroll
    for (int p = 0; p < 8; p++) s += v[p];
    #pragma unroll
    for (int o = 32; o; o >>= 1) s += __shfl_xor(s, o, 64);
    const float mean = s * (1.0f / 512.0f);

    float d[8], vs = 0.f;
    #pragma unroll
    for (int p = 0; p < 8; p++) { d[p] = v[p] - mean; vs += d[p] * d[p]; }
    #pragma unroll
    for (int o = 32; o; o >>= 1) vs += __shfl_xor(vs, o, 64);
    const float rstd = rsqrtf(vs * (1.0f / 512.0f) + 1e-5f);

    const float4 g0 = *(const float4*)(g + c),  g1 = *(const float4*)(g + c + 4);
    const float4 b0 = *(const float4*)(be + c), b1 = *(const float4*)(be + c + 4);

    const int el = r >> 2;
    const int b  = r & 3;
    float* orow = out + ((size_t)b * LL + e0 + el) * CC + c;
    float4 y0, y1;
    y0.x = d[0] * rstd * g0.x + b0.x;
    y0.y = d[1] * rstd * g0.y + b0.y;
    y0.z = d[2] * rstd * g0.z + b0.z;
    y0.w = d[3] * rstd * g0.w + b0.w;
    y1.x = d[4] * rstd * g1.x + b1.x;
    y1.y = d[5] * rstd * g1.y + b1.y;
    y1.z = d[6] * rstd * g1.z + b1.z;
    y1.w = d[7] * rstd * g1.w + b1.w;
    *(float4*)(orow)     = y0;
    *(float4*)(orow + 4) = y1;
}

// ---------------------------------------------------------------------------
extern "C" void kernel_launch(void* const* d_in, const int* in_sizes, int n_in,
                              void* d_out, int out_size, void* d_ws, size_t ws_size,
                              hipStream_t stream)
{
    const float* x       = (const float*)d_in[0];
    const float* eattr   = (const float*)d_in[1];
    const float* ts      = (const float*)d_in[2];
    const float* W_node  = (const float*)d_in[3];
    const float* b_node  = (const float*)d_in[4];
    const float* W_temb  = (const float*)d_in[5];
    const float* b_temb  = (const float*)d_in[6];
    const float* W_timef = (const float*)d_in[7];
    const float* b_timef = (const float*)d_in[8];
    const float* W_edge  = (const float*)d_in[9];
    const float* b_edge  = (const float*)d_in[10];
    const float* Wq      = (const float*)d_in[11];
    const float* bq      = (const float*)d_in[12];
    const float* Wk      = (const float*)d_in[13];
    const float* bk      = (const float*)d_in[14];
    const float* Wv      = (const float*)d_in[15];
    const float* bv      = (const float*)d_in[16];
    const float* Wo      = (const float*)d_in[17];
    const float* bo      = (const float*)d_in[18];
    const float* W1      = (const float*)d_in[19];
    const float* b1      = (const float*)d_in[20];
    const float* W2      = (const float*)d_in[21];
    const float* b2      = (const float*)d_in[22];
    const float* g1      = (const float*)d_in[23];
    const float* be1     = (const float*)d_in[24];
    const float* g2      = (const float*)d_in[25];
    const float* be2     = (const float*)d_in[26];
    const int*   ei      = (const int*)d_in[27];

    float* out = (float*)d_out;

    // ---- weight region (bf16) at front of ws ----
    u16* wnq_cat = (u16*)d_ws;              // 1024x512  [W_node ; Wq@W_node]
    u16* wkv_cat = wnq_cat + 524288;        // 1024x256  block-diag [Wk@W_timef | Wv@W_edge]
    u16* wo      = wkv_cat + 262144;        // 512x512
    u16* w1b     = wo + 262144;             // 2048x512
    u16* w2b     = w1b + 1048576;           // 512x2048
    float* bias_nq = (float*)(w2b + 1048576);   // 1024
    float* bias_kv = bias_nq + 1024;            // 1024
    char*  cbase   = (char*)(bias_kv + 1024);
    const size_t fixedB = (size_t)(cbase - (char*)d_ws);

    // ---- chunk sizing: per edge = 4 rows x 4096 u16 = 32768 B ----
    const size_t availB = (ws_size > fixedB) ? (ws_size - fixedB) : 0;
    int Ec = (int)(availB / 32768);
    Ec = (Ec / 64) * 64;                    // rows multiple of 256
    if (Ec > LL) Ec = LL;
    if (Ec < 64) Ec = 64;

    const size_t rmax = (size_t)4 * Ec;
    u16* An   = (u16*)cbase;                // rows x 512  (A_node -> ctx -> out1)
    u16* nodq = An + rmax * 512;            // rows x 1024 [nodef | q]
    u16* R    = nodq + rmax * 1024;         // rows x 2048 overlay
    u16* Akv  = R;                          // rows x 256
    u16* kv   = R + rmax * 256;             // rows x 1024 [k | v]
    u16* hid  = R;                          // rows x 2048 (Akv,kv dead by then)
    u16* aout = R + rmax * 2048;            // rows x 512  attn_out -> ffn

    GatherArgs ga{x, ts, W_temb, b_temb, eattr, ei};
    const dim3 blk(256);
    const dim3 gblk(512);

    // ---- weight prep ----
    cvt_bf   <<<dim3(256),  blk, 0, stream>>>(W_node, wnq_cat, 262144);
    comb_w_bf<<<dim3(1024), blk, 0, stream>>>(Wq, W_node, wnq_cat + 262144, 512, 512);
    zero_u16 <<<dim3(1024), blk, 0, stream>>>(wkv_cat, 262144);
    comb_w_bf<<<dim3(256),  blk, 0, stream>>>(Wk, W_timef, wkv_cat, 128, 256);
    comb_w_bf<<<dim3(256),  blk, 0, stream>>>(Wv, W_edge, wkv_cat + 512 * 256 + 128, 128, 256);
    cvt_bf   <<<dim3(256),  blk, 0, stream>>>(Wo, wo,  262144);
    cvt_bf   <<<dim3(1024), blk, 0, stream>>>(W1, w1b, 1048576);
    cvt_bf   <<<dim3(1024), blk, 0, stream>>>(W2, w2b, 1048576);
    copy_f32 <<<dim3(2),    blk, 0, stream>>>(b_node, bias_nq, 512);
    comb_b   <<<dim3(2),    blk, 0, stream>>>(Wq, b_node,  bq, bias_nq + 512);
    comb_b   <<<dim3(2),    blk, 0, stream>>>(Wk, b_timef, bk, bias_kv);
    comb_b   <<<dim3(2),    blk, 0, stream>>>(Wv, b_edge,  bv, bias_kv + 512);

    for (int e0 = 0; e0 < LL; e0 += Ec) {
        int ec = LL - e0; if (ec > Ec) ec = Ec;
        const int rows = 4 * ec;
        const int gy = rows / 256;

        prep_kernel<<<dim3(rows), blk, 0, stream>>>(An, Akv, e0, ga);

        // [nodef|q] = An @ wnq_cat^T ; [k|v] = Akv @ wkv_cat^T
        gemm_mfma<false><<<dim3(4, gy), gblk, 0, stream>>>(An,  wnq_cat, bias_nq, nodq, 1024, 512);
        gemm_mfma<false><<<dim3(4, gy), gblk, 0, stream>>>(Akv, wkv_cat, bias_kv, kv,   1024, 256);

        attn_kernel<<<dim3(ec / 4), blk, 0, stream>>>(nodq, kv, An /*ctx*/);

        // attn_out = ctx @ Wo^T + bo ; out1 = LN(nodef + attn_out) -> An (bf16)
        gemm_mfma<false><<<dim3(2, gy), gblk, 0, stream>>>(An, wo, bo, aout, 512, 512);
        ln1_kernel<<<dim3(rows / 4), blk, 0, stream>>>(nodq, aout, g1, be1, An /*out1*/);

        // FFN: hid = gelu(out1 @ W1^T) ; ffn = hid @ W2^T -> aout
        gemm_mfma<true ><<<dim3(8, gy), gblk, 0, stream>>>(An,  w1b, b1, hid, 2048, 512);
        gemm_mfma<false><<<dim3(2, gy), gblk, 0, stream>>>(hid, w2b, b2, aout /*ffn*/, 512, 2048);

        ln2_kernel<<<dim3(rows / 4), blk, 0, stream>>>(An, aout, g2, be2, out, e0);
    }
}

// Round 12
// 1137.725 us; speedup vs baseline: 1.6799x; 1.1680x over previous
//
#include <hip/hip_runtime.h>
#include <math.h>

#define BB 4
#define NN 2048
#define EE 16384
#define LL (EE + NN)      // 18432
#define ND_ 256
#define ED_ 128
#define TD_ 64
#define CC 512
#define HH 8
#define DH_ 64
#define C4 2048

typedef unsigned short u16;
typedef unsigned int u32;
typedef __bf16 bhalf8 __attribute__((ext_vector_type(8)));
typedef float f32x4 __attribute__((ext_vector_type(4)));

__device__ __forceinline__ u16 f2bf(float f) {
    union { float f; unsigned u; } c; c.f = f;
    const unsigned r = (c.u + 0x7fffu + ((c.u >> 16) & 1u)) >> 16;   // RNE
    return (u16)r;
}
__device__ __forceinline__ u16 f2bf_hw(float f) {      // native cvt (RNE)
    __bf16 h = (__bf16)f;
    union { __bf16 h; u16 u; } c; c.h = h; return c.u;
}
__device__ __forceinline__ float bf2f(u16 u) {
    union { unsigned u; float f; } c; c.u = ((unsigned)u) << 16; return c.f;
}
// tanh-form GELU: |err vs exact-erf gelu| ~3e-4, far below bf16 rounding
__device__ __forceinline__ float gelu_fast(float v) {
    const float u = v * (0.7978845608f + 0.0356774081f * v * v);
    const float e = __expf(2.0f * u);
    const float t = 1.0f - 2.0f / (e + 1.0f);
    return 0.5f * v * (1.0f + t);
}

#define GLD16(gp, lp) __builtin_amdgcn_global_load_lds( \
    (const __attribute__((address_space(1))) unsigned int*)(gp), \
    (__attribute__((address_space(3))) unsigned int*)(lp), 16, 0, 0)

// ---------------------------------------------------------------------------
// bf16 MFMA GEMM — 8-phase schedule (identical to rounds 9/10, replay-proven):
//   Y[M x N](bf16) = A[M x K] @ W[N x K]^T + bias(f32)
// 256x256 block, 512 thr = 8 waves, BK=64, dbuf 128 KB LDS, counted vmcnt(4),
// T2 XOR swizzle (0 bank conflicts). M%256==0, N%256==0, K%64==0, K>=256
// (NT>=4 — NT=2 never exercised; round-11 defensive constraint).
// ---------------------------------------------------------------------------
template<bool GELU>
__global__ __launch_bounds__(512, 2)
void gemm_mfma(const u16* __restrict__ A, const u16* __restrict__ W,
               const float* __restrict__ bias, u16* __restrict__ Y,
               int N, int K)
{
    __shared__ u16 As[2][16384];
    __shared__ u16 Bs[2][16384];

    const int o    = blockIdx.y * gridDim.x + blockIdx.x;
    const int nwg  = gridDim.x * gridDim.y;
    const int xcd  = o & 7;
    const int qq   = nwg >> 3, rr = nwg & 7;
    const int wg   = (xcd < rr ? xcd * (qq + 1) : rr * (qq + 1) + (xcd - rr) * qq) + (o >> 3);
    const int bx   = wg % gridDim.x;
    const int by   = wg / gridDim.x;
    const int m0   = by * 256;
    const int n0   = bx * 256;

    const int tid  = threadIdx.x;
    const int lane = tid & 63;
    const int wid  = tid >> 6;
    const int wm   = wid >> 2;
    const int wn   = wid & 3;

    const int swz8 = (((tid & 7) ^ ((tid >> 3) & 7))) * 8;
    const size_t sK = (size_t)K;
    const u16* Agb = A + (size_t)(m0 + (tid >> 3)) * sK + swz8;
    const u16* Wgb = W + (size_t)(n0 + (tid >> 3)) * sK + swz8;

    const int NT  = K >> 6;
    const int rlo = lane & 15;
    const int hi4 = lane >> 4;
    const int lk  = lane & 7;

#define STAGE_A(kt, h) do {                                      \
    const u16* _g = Agb + (size_t)(kt) * 64 + (size_t)(h) * 128 * sK; \
    u16* _l = &As[(kt) & 1][(h) * 8192 + tid * 8];               \
    GLD16(_g,           _l);                                     \
    GLD16(_g + 64 * sK, _l + 4096);                              \
} while (0)
#define STAGE_B(kt, h) do {                                      \
    const u16* _g = Wgb + (size_t)(kt) * 64 + (size_t)(h) * 128 * sK; \
    u16* _l = &Bs[(kt) & 1][(h) * 8192 + tid * 8];               \
    GLD16(_g,           _l);                                     \
    GLD16(_g + 64 * sK, _l + 4096);                              \
} while (0)

#define SWZOFF(ks) (((((ks) << 2) | hi4) ^ lk) << 3)
#define RD(buf, row, ks) (*(const bhalf8*)&(buf)[(row) * 64 + SWZOFF(ks)])

#define PHASE_SYNC() do {                                        \
    __builtin_amdgcn_sched_barrier(0);                           \
    __builtin_amdgcn_s_barrier();                                \
    asm volatile("s_waitcnt lgkmcnt(0)" ::: "memory");           \
    __builtin_amdgcn_sched_barrier(0);                           \
} while (0)
#define PHASE_END() do {                                         \
    __builtin_amdgcn_sched_barrier(0);                           \
    __builtin_amdgcn_s_barrier();                                \
    __builtin_amdgcn_sched_barrier(0);                           \
} while (0)

    f32x4 acc[8][4] = {};

    STAGE_A(0, 0); STAGE_A(0, 1);
    STAGE_B(0, 0); STAGE_B(0, 1);
    STAGE_B(1, 0); STAGE_B(1, 1);
    asm volatile("s_waitcnt vmcnt(4)" ::: "memory");
    __builtin_amdgcn_s_barrier();
    __builtin_amdgcn_sched_barrier(0);

    for (int t = 0; t < NT; ++t) {
        const u16* as = &As[t & 1][0];
        const u16* bs = &Bs[t & 1][0];
        bhalf8 aLo[4][2], aHi[4][2], b0[2][2], b1[2][2];

        #pragma unroll
        for (int i = 0; i < 4; ++i) {
            aLo[i][0] = RD(as, wm * 128 + i * 16 + rlo, 0);
            aLo[i][1] = RD(as, wm * 128 + i * 16 + rlo, 1);
        }
        #pragma unroll
        for (int j = 0; j < 2; ++j) {
            b0[j][0] = RD(bs, wn * 64 + j * 16 + rlo, 0);
            b0[j][1] = RD(bs, wn * 64 + j * 16 + rlo, 1);
        }
        if (t + 1 < NT) STAGE_A(t + 1, 0);
        PHASE_SYNC();
        __builtin_amdgcn_s_setprio(1);
        #pragma unroll
        for (int i = 0; i < 4; ++i)
            #pragma unroll
            for (int j = 0; j < 2; ++j)
                #pragma unroll
                for (int ks = 0; ks < 2; ++ks)
                    acc[i][j] = __builtin_amdgcn_mfma_f32_16x16x32_bf16(b0[j][ks], aLo[i][ks], acc[i][j], 0, 0, 0);
        __builtin_amdgcn_s_setprio(0);
        PHASE_END();

        #pragma unroll
        for (int j = 0; j < 2; ++j) {
            b1[j][0] = RD(bs, wn * 64 + 32 + j * 16 + rlo, 0);
            b1[j][1] = RD(bs, wn * 64 + 32 + j * 16 + rlo, 1);
        }
        if (t + 1 < NT) STAGE_A(t + 1, 1);
        PHASE_SYNC();
        __builtin_amdgcn_s_setprio(1);
        #pragma unroll
        for (int i = 0; i < 4; ++i)
            #pragma unroll
            for (int j = 0; j < 2; ++j)
                #pragma unroll
                for (int ks = 0; ks < 2; ++ks)
                    acc[i][2 + j] = __builtin_amdgcn_mfma_f32_16x16x32_bf16(b1[j][ks], aLo[i][ks], acc[i][2 + j], 0, 0, 0);
        __builtin_amdgcn_s_setprio(0);
        PHASE_END();

        #pragma unroll
        for (int i = 0; i < 4; ++i) {
            aHi[i][0] = RD(as, wm * 128 + 64 + i * 16 + rlo, 0);
            aHi[i][1] = RD(as, wm * 128 + 64 + i * 16 + rlo, 1);
        }
        if (t + 2 < NT) STAGE_B(t + 2, 0);
        PHASE_SYNC();
        __builtin_amdgcn_s_setprio(1);
        #pragma unroll
        for (int i = 0; i < 4; ++i)
            #pragma unroll
            for (int j = 0; j < 2; ++j)
                #pragma unroll
                for (int ks = 0; ks < 2; ++ks)
                    acc[4 + i][j] = __builtin_amdgcn_mfma_f32_16x16x32_bf16(b0[j][ks], aHi[i][ks], acc[4 + i][j], 0, 0, 0);
        __builtin_amdgcn_s_setprio(0);
        PHASE_END();

        if (t + 2 < NT) {
            STAGE_B(t + 2, 1);
            asm volatile("s_waitcnt vmcnt(4)" ::: "memory");
        } else if (t < NT - 1) {
            asm volatile("s_waitcnt vmcnt(0)" ::: "memory");
        }
        PHASE_SYNC();
        __builtin_amdgcn_s_setprio(1);
        #pragma unroll
        for (int i = 0; i < 4; ++i)
            #pragma unroll
            for (int j = 0; j < 2; ++j)
                #pragma unroll
                for (int ks = 0; ks < 2; ++ks)
                    acc[4 + i][2 + j] = __builtin_amdgcn_mfma_f32_16x16x32_bf16(b1[j][ks], aHi[i][ks], acc[4 + i][2 + j], 0, 0, 0);
        __builtin_amdgcn_s_setprio(0);
        if (t < NT - 1) PHASE_END();
    }
#undef STAGE_A
#undef STAGE_B
#undef SWZOFF
#undef RD
#undef PHASE_SYNC
#undef PHASE_END

    const int row0 = m0 + wm * 128;
    const int col0 = n0 + wn * 64;
    const int rq   = (lane >> 4) * 4;
    float4 bi[4];
    #pragma unroll
    for (int j = 0; j < 4; ++j)
        bi[j] = *(const float4*)(bias + col0 + j * 16 + rq);

    #pragma unroll
    for (int i = 0; i < 8; ++i) {
        const int gr = row0 + i * 16 + rlo;
        u16* yrow = Y + (size_t)gr * N + col0;
        #pragma unroll
        for (int j = 0; j < 4; ++j) {
            float v0 = acc[i][j][0] + bi[j].x;
            float v1 = acc[i][j][1] + bi[j].y;
            float v2 = acc[i][j][2] + bi[j].z;
            float v3 = acc[i][j][3] + bi[j].w;
            if constexpr (GELU) {
                v0 = gelu_fast(v0); v1 = gelu_fast(v1);
                v2 = gelu_fast(v2); v3 = gelu_fast(v3);
            }
            ushort4 ov;
            ov.x = f2bf_hw(v0); ov.y = f2bf_hw(v1);
            ov.z = f2bf_hw(v2); ov.w = f2bf_hw(v3);
            *(ushort4*)(yrow + j * 16 + rq) = ov;
        }
    }
}

// ---------------------------------------------------------------------------
// Wbig builder: 2048x256 bf16.
// rows 0..511 = W_node[:,0:256]; 512..1023 = (Wq@W_node)[:,0:256];
// 1024..1535 = W_node[:,256:512]; 1536..2047 = (Wq@W_node)[:,256:512]
// ---------------------------------------------------------------------------
__global__ __launch_bounds__(256)
void build_wbig(const float* __restrict__ Wn, const float* __restrict__ Wq,
                u16* __restrict__ out)
{
    const int idx = blockIdx.x * 256 + threadIdx.x;   // 524288
    const int R = idx >> 8;
    const int k = idx & 255;
    float v;
    if (R < 512) {
        v = Wn[R * 512 + k];
    } else if (R < 1024) {
        const int c = R - 512; float a = 0.f;
        for (int j = 0; j < 512; j++) a += Wq[c * 512 + j] * Wn[j * 512 + k];
        v = a;
    } else if (R < 1536) {
        v = Wn[(R - 1024) * 512 + 256 + k];
    } else {
        const int c = R - 1536; float a = 0.f;
        for (int j = 0; j < 512; j++) a += Wq[c * 512 + j] * Wn[j * 512 + 256 + k];
        v = a;
    }
    out[idx] = f2bf(v);
}

// ---------------------------------------------------------------------------
// Wkt builder: 1024x256 bf16 (cols 128..255 zero padding), block-diag of
// wtk = Wk@W_timef: rows 0..511: [wtk[:,0:64] | 0...] ; 512..1023: [0 | wtk[:,64:128] | 0pad]
// ---------------------------------------------------------------------------
__global__ __launch_bounds__(256)
void build_wkt(const float* __restrict__ Wk, const float* __restrict__ Wtf,
               u16* __restrict__ out)
{
    const int idx = blockIdx.x * 256 + threadIdx.x;   // 262144
    const int R = idx >> 8;
    const int k = idx & 255;
    float v = 0.f;
    const bool live = (k < 128) && ((R < 512) ? (k < 64) : (k >= 64));
    if (live) {
        const int c = (R < 512) ? R : R - 512;
        float a = 0.f;
        for (int j = 0; j < 512; j++) a += Wk[c * 512 + j] * Wtf[j * 128 + k];
        v = a;
    }
    out[idx] = f2bf(v);
}

// ---------------------------------------------------------------------------
// TE: per-node time encoding, 256 cols (first 128 = dup sin enc, rest zero).
// ---------------------------------------------------------------------------
__global__ __launch_bounds__(256)
void te_kernel(const float* __restrict__ ts, const float* __restrict__ wtemb,
               const float* __restrict__ btemb, u16* __restrict__ TE)
{
    const int idx4 = (blockIdx.x * 256 + threadIdx.x) * 4;   // over 8192*256
    const int n = idx4 >> 8;
    const int j = idx4 & 255;
    ushort4 ov;
    if (j < 128) {
        const int kb = j & 63;
        const float tt = ts[n];
        ov.x = f2bf(sinf(tt * wtemb[kb + 0] + btemb[kb + 0]));
        ov.y = f2bf(sinf(tt * wtemb[kb + 1] + btemb[kb + 1]));
        ov.z = f2bf(sinf(tt * wtemb[kb + 2] + btemb[kb + 2]));
        ov.w = f2bf(sinf(tt * wtemb[kb + 3] + btemb[kb + 3]));
    } else {
        ov.x = ov.y = ov.z = ov.w = 0;
    }
    *(ushort4*)(TE + idx4) = ov;
}

// ---------------------------------------------------------------------------
// prep_e: edge-attr gather/convert into chunk rows (r = 4*el+b), 256 cols
// (128 data + 128 zero pad). 8 rows per 256-thr block, 32 lanes x 8 cols.
// ---------------------------------------------------------------------------
__global__ __launch_bounds__(256)
void prep_e(const float* __restrict__ eattr, u16* __restrict__ Ae, int e0)
{
    const int t  = threadIdx.x;
    const int r  = blockIdx.x * 8 + (t >> 5);
    const int cl = (t & 31) * 8;
    const int el = r >> 2;
    const int b  = r & 3;
    const int ge = e0 + el;
    uint4 ov;
    if (ge < EE && cl < 128) {
        const float* src = eattr + ((size_t)b * EE + ge) * 128 + cl;
        const float4 a = *(const float4*)src;
        const float4 c = *(const float4*)(src + 4);
        ov.x = (u32)f2bf(a.x) | ((u32)f2bf(a.y) << 16);
        ov.y = (u32)f2bf(a.z) | ((u32)f2bf(a.w) << 16);
        ov.z = (u32)f2bf(c.x) | ((u32)f2bf(c.y) << 16);
        ov.w = (u32)f2bf(c.z) | ((u32)f2bf(c.w) << 16);
    } else {
        ov.x = ov.y = ov.z = ov.w = 0;
    }
    *(uint4*)(Ae + (size_t)r * 256 + cl) = ov;
}

// ---------------------------------------------------------------------------
// helpers
// ---------------------------------------------------------------------------
__global__ __launch_bounds__(256)
void comb_w_bf(const float* __restrict__ Wa, const float* __restrict__ Wb,
               u16* __restrict__ out, int Kin, int ostride)
{
    const int idx  = blockIdx.x * 256 + threadIdx.x;
    const int c    = idx / Kin;
    const int kcol = idx - c * Kin;
    float acc = 0.f;
    for (int j = 0; j < CC; j++)
        acc += Wa[c * CC + j] * Wb[j * Kin + kcol];
    out[(size_t)c * ostride + kcol] = f2bf(acc);
}

__global__ __launch_bounds__(256)
void comb_b(const float* __restrict__ Wa, const float* __restrict__ bin,
            const float* __restrict__ ba, float* __restrict__ bout)
{
    const int c = blockIdx.x * 256 + threadIdx.x;
    float acc = ba[c];
    for (int j = 0; j < CC; j++)
        acc += Wa[c * CC + j] * bin[j];
    bout[c] = acc;
}

__global__ __launch_bounds__(256)
void cvt_bf(const float* __restrict__ in, u16* __restrict__ out, int n)
{
    const int i = (blockIdx.x * 256 + threadIdx.x) * 4;
    if (i < n) {
        const float4 v = *(const float4*)(in + i);
        ushort4 ov;
        ov.x = f2bf(v.x); ov.y = f2bf(v.y); ov.z = f2bf(v.z); ov.w = f2bf(v.w);
        *(ushort4*)(out + i) = ov;
    }
}

__global__ __launch_bounds__(256)
void zero_u16(u16* __restrict__ p, int n)
{
    const int i = blockIdx.x * 256 + threadIdx.x;
    if (i < n) p[i] = 0;
}

__global__ __launch_bounds__(256)
void copy_f32(const float* __restrict__ in, float* __restrict__ out, int n)
{
    const int i = blockIdx.x * 256 + threadIdx.x;
    if (i < n) out[i] = in[i];
}

// ---------------------------------------------------------------------------
// attn_fused: batch-axis attention with q/k gathered from per-node tables.
// q[r] = P[s][512:1024] + P[t][1536:2048] ; k[r] = KLR[s][0:512]+KLR[t][512:];
// v from kvv. Block = 4 edges x 64 lanes; ctx -> An.
// ---------------------------------------------------------------------------
__global__ __launch_bounds__(256)
void attn_fused(const u16* __restrict__ P, const u16* __restrict__ KLR,
                const u16* __restrict__ kvv, const int* __restrict__ ei,
                u16* __restrict__ ctx, int e0)
{
    const int el   = blockIdx.x * 4 + (threadIdx.x >> 6);
    const int ge   = e0 + el;
    const int lane = threadIdx.x & 63;
    const int off  = (lane >> 3) * 64 + (lane & 7) * 8;

    float qf[4][8], kf[4][8], vf[4][8];
    #pragma unroll
    for (int l = 0; l < 4; l++) {
        int s, t;
        if (ge < EE) {
            s = ei[(l * 2 + 0) * EE + ge];
            t = ei[(l * 2 + 1) * EE + ge];
        } else {
            s = t = ge - EE;
        }
        const size_t ns = (size_t)(l * NN + s);
        const size_t nt = (size_t)(l * NN + t);
        const uint4 qs = *(const uint4*)(P + ns * 2048 + 512 + off);
        const uint4 qt = *(const uint4*)(P + nt * 2048 + 1536 + off);
        const uint4 ks = *(const uint4*)(KLR + ns * 1024 + off);
        const uint4 kt = *(const uint4*)(KLR + nt * 1024 + 512 + off);
        const uint4 vx = *(const uint4*)(kvv + (size_t)(4 * el + l) * 512 + off);
        const u32 qa[4] = {qs.x, qs.y, qs.z, qs.w};
        const u32 qb[4] = {qt.x, qt.y, qt.z, qt.w};
        const u32 ka[4] = {ks.x, ks.y, ks.z, ks.w};
        const u32 kb[4] = {kt.x, kt.y, kt.z, kt.w};
        const u32 va[4] = {vx.x, vx.y, vx.z, vx.w};
        #pragma unroll
        for (int p = 0; p < 4; p++) {
            qf[l][2*p]   = bf2f((u16)qa[p])         + bf2f((u16)qb[p]);
            qf[l][2*p+1] = bf2f((u16)(qa[p] >> 16)) + bf2f((u16)(qb[p] >> 16));
            kf[l][2*p]   = bf2f((u16)ka[p])         + bf2f((u16)kb[p]);
            kf[l][2*p+1] = bf2f((u16)(ka[p] >> 16)) + bf2f((u16)(kb[p] >> 16));
            vf[l][2*p]   = bf2f((u16)va[p]);
            vf[l][2*p+1] = bf2f((u16)(va[p] >> 16));
        }
    }

    float sc[4][4];
    #pragma unroll
    for (int l = 0; l < 4; l++) {
        #pragma unroll
        for (int m = 0; m < 4; m++) {
            float p = 0.f;
            #pragma unroll
            for (int d = 0; d < 8; d++) p += qf[l][d] * kf[m][d];
            p += __shfl_xor(p, 1, 64);
            p += __shfl_xor(p, 2, 64);
            p += __shfl_xor(p, 4, 64);
            sc[l][m] = p * 0.125f;
        }
    }

    #pragma unroll
    for (int l = 0; l < 4; l++) {
        const float mx = fmaxf(fmaxf(sc[l][0], sc[l][1]), fmaxf(sc[l][2], sc[l][3]));
        float a[4], s = 0.f;
        #pragma unroll
        for (int m = 0; m < 4; m++) { a[m] = __expf(sc[l][m] - mx); s += a[m]; }
        const float inv = 1.0f / s;
        float cv[8];
        #pragma unroll
        for (int d = 0; d < 8; d++) {
            cv[d] = (a[0] * vf[0][d] + a[1] * vf[1][d] +
                     a[2] * vf[2][d] + a[3] * vf[3][d]) * inv;
        }
        ushort4 o0, o1;
        o0.x = f2bf(cv[0]); o0.y = f2bf(cv[1]); o0.z = f2bf(cv[2]); o0.w = f2bf(cv[3]);
        o1.x = f2bf(cv[4]); o1.y = f2bf(cv[5]); o1.z = f2bf(cv[6]); o1.w = f2bf(cv[7]);
        u16* crow = ctx + (size_t)(4 * el + l) * 512 + off;
        *(ushort4*)crow       = o0;
        *(ushort4*)(crow + 4) = o1;
    }
}

// ---------------------------------------------------------------------------
// ln1_fused (wave-per-row): out1 = LN(nodef + attn_out) -> bf16,
// nodef[r] = P[s][0:512] + P[t][1024:1536] gathered on the fly.
// ---------------------------------------------------------------------------
__global__ __launch_bounds__(256)
void ln1_fused(const u16* __restrict__ P, const u16* __restrict__ aout,
               const int* __restrict__ ei,
               const float* __restrict__ g, const float* __restrict__ be,
               u16* __restrict__ outb, int e0)
{
    const int r    = blockIdx.x * 4 + (threadIdx.x >> 6);
    const int lane = threadIdx.x & 63;
    const int c    = lane * 8;
    const int el   = r >> 2;
    const int b    = r & 3;
    const int ge   = e0 + el;

    int s, t;
    if (ge < EE) {
        s = ei[(b * 2 + 0) * EE + ge];
        t = ei[(b * 2 + 1) * EE + ge];
    } else {
        s = t = ge - EE;
    }

    const uint4 nfs = *(const uint4*)(P + (size_t)(b * NN + s) * 2048 + c);
    const uint4 nft = *(const uint4*)(P + (size_t)(b * NN + t) * 2048 + 1024 + c);
    const uint4 ao  = *(const uint4*)(aout + (size_t)r * 512 + c);
    const u32 na[4] = {nfs.x, nfs.y, nfs.z, nfs.w};
    const u32 nb[4] = {nft.x, nft.y, nft.z, nft.w};
    const u32 aa[4] = {ao.x, ao.y, ao.z, ao.w};

    float v[8];
    #pragma unroll
    for (int p = 0; p < 4; p++) {
        v[2*p]   = bf2f((u16)na[p])         + bf2f((u16)nb[p])         + bf2f((u16)aa[p]);
        v[2*p+1] = bf2f((u16)(na[p] >> 16)) + bf2f((u16)(nb[p] >> 16)) + bf2f((u16)(aa[p] >> 16));
    }

    float sum = 0.f;
    #pragma unroll
    for (int p = 0; p < 8; p++) sum += v[p];
    #pragma unroll
    for (int o = 32; o; o >>= 1) sum += __shfl_xor(sum, o, 64);
    const float mean = sum * (1.0f / 512.0f);

    float d[8], vs = 0.f;
    #pragma unroll
    for (int p = 0; p < 8; p++) { d[p] = v[p] - mean; vs += d[p] * d[p]; }
    #pragma unroll
    for (int o = 32; o; o >>= 1) vs += __shfl_xor(vs, o, 64);
    const float rstd = rsqrtf(vs * (1.0f / 512.0f) + 1e-5f);

    const float4 g0 = *(const float4*)(g + c),  g1 = *(const float4*)(g + c + 4);
    const float4 b0 = *(const float4*)(be + c), b1 = *(const float4*)(be + c + 4);
    const float gg[8] = {g0.x, g0.y, g0.z, g0.w, g1.x, g1.y, g1.z, g1.w};
    const float bb[8] = {b0.x, b0.y, b0.z, b0.w, b1.x, b1.y, b1.z, b1.w};

    uint4 ov;
    u32 w[4];
    #pragma unroll
    for (int p = 0; p < 4; p++) {
        const float y0 = d[2*p]   * rstd * gg[2*p]   + bb[2*p];
        const float y1 = d[2*p+1] * rstd * gg[2*p+1] + bb[2*p+1];
        w[p] = (u32)f2bf(y0) | ((u32)f2bf(y1) << 16);
    }
    ov.x = w[0]; ov.y = w[1]; ov.z = w[2]; ov.w = w[3];
    *(uint4*)(outb + (size_t)r * 512 + c) = ov;
}

// ---------------------------------------------------------------------------
// ln2 (wave-per-row): d_out[grow] = LN(out1 + ffn), f32 out.
// ---------------------------------------------------------------------------
__global__ __launch_bounds__(256)
void ln2_kernel(const u16* __restrict__ out1, const u16* __restrict__ ffn,
                const float* __restrict__ g, const float* __restrict__ be,
                float* __restrict__ out, int e0)
{
    const int r    = blockIdx.x * 4 + (threadIdx.x >> 6);
    const int lane = threadIdx.x & 63;
    const int c    = lane * 8;

    const uint4 o1 = *(const uint4*)(out1 + (size_t)r * 512 + c);
    const uint4 ff = *(const uint4*)(ffn  + (size_t)r * 512 + c);
    const u32 oa[4] = {o1.x, o1.y, o1.z, o1.w};
    const u32 fa[4] = {ff.x, ff.y, ff.z, ff.w};

    float v[8];
    #pragma unroll
    for (int p = 0; p < 4; p++) {
        v[2*p]   = bf2f((u16)oa[p])         + bf2f((u16)fa[p]);
        v[2*p+1] = bf2f((u16)(oa[p] >> 16)) + bf2f((u16)(fa[p] >> 16));
    }

    float s = 0.f;
    #pragma unroll
    for (int p = 0; p < 8; p++) s += v[p];
    #pragma unroll
    for (int o = 32; o; o >>= 1) s += __shfl_xor(s, o, 64);
    const float mean = s * (1.0f / 512.0f);

    float d[8], vs = 0.f;
    #pragma unroll
    for (int p = 0; p < 8; p++) { d[p] = v[p] - mean; vs += d[p] * d[p]; }
    #pragma unroll
    for (int o = 32; o; o >>= 1) vs += __shfl_xor(vs, o, 64);
    const float rstd = rsqrtf(vs * (1.0f / 512.0f) + 1e-5f);

    const float4 g0 = *(const float4*)(g + c),  g1 = *(const float4*)(g + c + 4);
    const float4 b0 = *(const float4*)(be + c), b1 = *(const float4*)(be + c + 4);

    const int el = r >> 2;
    const int b  = r & 3;
    float* orow = out + ((size_t)b * LL + e0 + el) * CC + c;
    float4 y0, y1;
    y0.x = d[0] * rstd * g0.x + b0.x;
    y0.y = d[1] * rstd * g0.y + b0.y;
    y0.z = d[2] * rstd * g0.z + b0.z;
    y0.w = d[3] * rstd * g0.w + b0.w;
    y1.x = d[4] * rstd * g1.x + b1.x;
    y1.y = d[5] * rstd * g1.y + b1.y;
    y1.z = d[6] * rstd * g1.z + b1.z;
    y1.w = d[7] * rstd * g1.w + b1.w;
    *(float4*)(orow)     = y0;
    *(float4*)(orow + 4) = y1;
}

// ---------------------------------------------------------------------------
extern "C" void kernel_launch(void* const* d_in, const int* in_sizes, int n_in,
                              void* d_out, int out_size, void* d_ws, size_t ws_size,
                              hipStream_t stream)
{
    const float* x       = (const float*)d_in[0];
    const float* eattr   = (const float*)d_in[1];
    const float* ts      = (const float*)d_in[2];
    const float* W_node  = (const float*)d_in[3];
    const float* b_node  = (const float*)d_in[4];
    const float* W_temb  = (const float*)d_in[5];
    const float* b_temb  = (const float*)d_in[6];
    const float* W_timef = (const float*)d_in[7];
    const float* b_timef = (const float*)d_in[8];
    const float* W_edge  = (const float*)d_in[9];
    const float* b_edge  = (const float*)d_in[10];
    const float* Wq      = (const float*)d_in[11];
    const float* bq      = (const float*)d_in[12];
    const float* Wk      = (const float*)d_in[13];
    const float* bk      = (const float*)d_in[14];
    const float* Wv      = (const float*)d_in[15];
    const float* bv      = (const float*)d_in[16];
    const float* Wo      = (const float*)d_in[17];
    const float* bo      = (const float*)d_in[18];
    const float* W1      = (const float*)d_in[19];
    const float* b1      = (const float*)d_in[20];
    const float* W2      = (const float*)d_in[21];
    const float* b2      = (const float*)d_in[22];
    const float* g1      = (const float*)d_in[23];
    const float* be1     = (const float*)d_in[24];
    const float* g2      = (const float*)d_in[25];
    const float* be2     = (const float*)d_in[26];
    const int*   ei      = (const int*)d_in[27];

    float* out = (float*)d_out;

    // ---- fixed region (u16 units) ----
    u16* wbig = (u16*)d_ws;                 // 2048x256  = 524288
    u16* wkt  = wbig + 524288;              // 1024x256  = 262144 (zero-padded)
    u16* wev  = wkt + 262144;               // 512x256   = 131072 (zero-padded)
    u16* wo   = wev + 131072;               // 512x512   = 262144
    u16* w1b  = wo + 262144;                // 2048x512  = 1048576
    u16* w2b  = w1b + 1048576;              // 512x2048  = 1048576
    u16* xb   = w2b + 1048576;              // 8192x256  = 2097152
    u16* TE   = xb + 2097152;               // 8192x256  = 2097152 (zero-padded)
    u16* P    = TE + 2097152;               // 8192x2048 = 16777216
    u16* KLR  = P + 16777216;               // 8192x1024 = 8388608
    float* bias2048 = (float*)(KLR + 8388608);  // 2048
    float* biasKLR  = bias2048 + 2048;          // 1024
    float* bev      = biasKLR + 1024;           // 512
    char*  cbase    = (char*)(bev + 512);
    const size_t fixedB = (size_t)(cbase - (char*)d_ws);

    // ---- chunk sizing: per edge = 4 rows x (256+512*3+2048) u16 = 30720 B --
    const size_t availB = (ws_size > fixedB) ? (ws_size - fixedB) : 0;
    int Ec = (int)(availB / 30720);
    Ec = (Ec / 64) * 64;                    // rows multiple of 256
    if (Ec > LL) Ec = LL;
    if (Ec < 64) Ec = 64;

    const size_t rmax = (size_t)4 * Ec;
    u16* Ae   = (u16*)cbase;                // rows x 256 (dedicated, no overlay)
    u16* kvv  = Ae + rmax * 256;            // rows x 512 (v)
    u16* An   = kvv + rmax * 512;           // rows x 512 (ctx -> out1)
    u16* aout = An + rmax * 512;            // rows x 512 (attn_out -> ffn)
    u16* hid  = aout + rmax * 512;          // rows x 2048

    const dim3 blk(256);
    const dim3 gblk(512);

    // ---- global precompute ----
    cvt_bf    <<<dim3(2048), blk, 0, stream>>>(x, xb, 2097152);
    build_wbig<<<dim3(2048), blk, 0, stream>>>(W_node, Wq, wbig);
    copy_f32  <<<dim3(2),    blk, 0, stream>>>(b_node, bias2048, 512);
    comb_b    <<<dim3(2),    blk, 0, stream>>>(Wq, b_node, bq, bias2048 + 512);
    zero_u16  <<<dim3(8),    blk, 0, stream>>>((u16*)(bias2048 + 1024), 2048);
    gemm_mfma<false><<<dim3(8, 32), gblk, 0, stream>>>(xb, wbig, bias2048, P, 2048, 256);

    te_kernel <<<dim3(2048), blk, 0, stream>>>(ts, W_temb, b_temb, TE);
    build_wkt <<<dim3(1024), blk, 0, stream>>>(Wk, W_timef, wkt);
    comb_b    <<<dim3(2),    blk, 0, stream>>>(Wk, b_timef, bk, biasKLR);
    zero_u16  <<<dim3(4),    blk, 0, stream>>>((u16*)(biasKLR + 512), 1024);
    gemm_mfma<false><<<dim3(4, 32), gblk, 0, stream>>>(TE, wkt, biasKLR, KLR, 1024, 256);

    zero_u16  <<<dim3(512),  blk, 0, stream>>>(wev, 131072);
    comb_w_bf <<<dim3(256),  blk, 0, stream>>>(Wv, W_edge, wev, 128, 256);
    comb_b    <<<dim3(2),    blk, 0, stream>>>(Wv, b_edge, bv, bev);
    cvt_bf    <<<dim3(256),  blk, 0, stream>>>(Wo, wo,  262144);
    cvt_bf    <<<dim3(1024), blk, 0, stream>>>(W1, w1b, 1048576);
    cvt_bf    <<<dim3(1024), blk, 0, stream>>>(W2, w2b, 1048576);

    for (int e0 = 0; e0 < LL; e0 += Ec) {
        int ec = LL - e0; if (ec > Ec) ec = Ec;
        const int rows = 4 * ec;
        const int gy = rows / 256;

        prep_e<<<dim3(rows / 8), blk, 0, stream>>>(eattr, Ae, e0);

        // v = Ae @ wev^T + bev   (K padded to 256, NT=4)
        gemm_mfma<false><<<dim3(2, gy), gblk, 0, stream>>>(Ae, wev, bev, kvv, 512, 256);

        // attention with gathered q/k ; ctx -> An
        attn_fused<<<dim3(ec / 4), blk, 0, stream>>>(P, KLR, kvv, ei, An, e0);

        // attn_out = ctx @ Wo^T + bo ; out1 = LN(gathered nodef + attn_out)
        gemm_mfma<false><<<dim3(2, gy), gblk, 0, stream>>>(An, wo, bo, aout, 512, 512);
        ln1_fused<<<dim3(rows / 4), blk, 0, stream>>>(P, aout, ei, g1, be1, An, e0);

        // FFN
        gemm_mfma<true ><<<dim3(8, gy), gblk, 0, stream>>>(An,  w1b, b1, hid, 2048, 512);
        gemm_mfma<false><<<dim3(2, gy), gblk, 0, stream>>>(hid, w2b, b2, aout, 512, 2048);

        ln2_kernel<<<dim3(rows / 4), blk, 0, stream>>>(An, aout, g2, be2, out, e0);
    }
}